// Round 3
// baseline (480.672 us; speedup 1.0000x reference)
//
#include <hip/hip_runtime.h>
#include <cstddef>

// ButterFlyNet2D IDFT forward. Split-bf16 MFMA (3-pass: Whi*Yhi + Whi*Ylo + Wlo*Yhi).
// Activations between layers stored as TWO bf16 planes (hi, lo), each PLANE elements:
//   plane layout A[gy][gx][i][k][l][b][p][q] -> per block contiguous Y[256][Nb].
// Weights for layers 1-3 pre-converted once into bf16 hi/lo planes (heavy reuse);
// layers 4-5 convert in-kernel (reuse <= 2, HBM-bound anyway).

typedef unsigned short ushort_t;
typedef __attribute__((ext_vector_type(8))) short bf16x8;
typedef __attribute__((ext_vector_type(4))) float f32x4;

#define PLANE 16777216   // elements per activation plane (all layer boundaries)

__device__ inline ushort_t bf16_rn(float x) {
    unsigned u = __builtin_bit_cast(unsigned, x);
    unsigned r = (u + 0x7FFFu + ((u >> 16) & 1u)) >> 16;
    return (ushort_t)r;
}
__device__ inline float bf16_to_f(ushort_t h) {
    unsigned u = ((unsigned)h) << 16;
    return __builtin_bit_cast(float, u);
}

// ---------------- weight pre-convert (layers 1-3) ----------------
__global__ __launch_bounds__(256)
void wconv_kernel(const float* __restrict__ src, ushort_t* __restrict__ hi,
                  ushort_t* __restrict__ lo, int n8) {
    const int i = blockIdx.x * 256 + threadIdx.x;
    if (i >= n8) return;
    const float4 a = *(const float4*)(src + 8 * i);
    const float4 b = *(const float4*)(src + 8 * i + 4);
    union { bf16x8 v; ushort_t u[8]; } H, L;
    const float f[8] = {a.x, a.y, a.z, a.w, b.x, b.y, b.z, b.w};
#pragma unroll
    for (int e = 0; e < 8; ++e) {
        const ushort_t h = bf16_rn(f[e]);
        H.u[e] = h;
        L.u[e] = bf16_rn(f[e] - bf16_to_f(h));
    }
    *(bf16x8*)(hi + 8 * i) = H.v;
    *(bf16x8*)(lo + 8 * i) = L.v;
}

// ---------------- Layer 0 (scalar, writes split-bf16 planes) ----------------
__global__ __launch_bounds__(256)
void layer0_kernel(const float* __restrict__ xr, const float* __restrict__ xi,
                   const float* __restrict__ w0, const float* __restrict__ b0,
                   ushort_t* __restrict__ A1) {
    const int o = blockIdx.y;                      // 0..255
    const int n = blockIdx.x * 256 + threadIdx.x;  // (b,p,q)
    const int b = n >> 10;
    const int p = (n >> 5) & 31;
    const int q = n & 31;
    const float* wrow = w0 + o * 16;
    float acc = b0[o];
#pragma unroll
    for (int k = 0; k < 2; ++k) {
#pragma unroll
        for (int l = 0; l < 2; ++l) {
            const int idx = b * 4096 + (2 * p + k) * 64 + (2 * q + l);
            const float vr = xr[idx], vi = xi[idx];
            acc = fmaf(fmaxf(vr, 0.f),  wrow[0  + k * 2 + l], acc);
            acc = fmaf(fmaxf(vi, 0.f),  wrow[4  + k * 2 + l], acc);
            acc = fmaf(fmaxf(-vr, 0.f), wrow[8  + k * 2 + l], acc);
            acc = fmaf(fmaxf(-vi, 0.f), wrow[12 + k * 2 + l], acc);
        }
    }
    acc = fmaxf(acc, 0.f);
    const int gy = o >> 7, gx = (o >> 6) & 1, c = o & 63;
    const int kp = p & 1, lp = q & 1, pp = p >> 1, qp = q >> 1;
    const size_t flat = (size_t)((((gy * 2 + gx) * 64 + c) * 2 + kp) * 2 + lp) * (64 * 256)
                      + (size_t)(b * 256 + pp * 16 + qp);
    const ushort_t h = bf16_rn(acc);
    A1[flat]         = h;
    A1[flat + PLANE] = bf16_rn(acc - bf16_to_f(h));
}

// ---------------- Recursion layers 1..5 : split-bf16 MFMA ----------------
// 256 threads = 4 waves; computes C[256][NT] for one (block, ntile).
template<int NT, bool PRECONV>
__global__ __launch_bounds__(256, 2)
void rec_mfma_kernel(const ushort_t* __restrict__ Yg,      // hi plane; lo at +PLANE
                     const float* __restrict__ Wf,          // f32 weights (if !PRECONV)
                     const ushort_t* __restrict__ Whi_g,    // bf16 planes (if PRECONV)
                     const ushort_t* __restrict__ Wlo_g,
                     const float* __restrict__ bias,
                     ushort_t* __restrict__ Aout,           // hi plane; lo at +PLANE
                     const int lgG, const int lgS2, const int isLast) {
    constexpr int NF   = NT / 16;
    constexpr int KSEG = 32 / (256 / NT);   // k-rows per thread in Y staging
    constexpr int LD   = 40;                // LDS row stride (shorts): 2-way max banks

    __shared__ ushort_t Whi_s[256 * LD];
    __shared__ ushort_t Wlo_s[256 * LD];
    __shared__ ushort_t Yhi_s[NT * LD];
    __shared__ ushort_t Ylo_s[NT * LD];

    const int G  = 1 << lgG;
    const int S2 = 1 << lgS2;
    const int Nb = 64 << (2 * lgS2);

    const int bid = blockIdx.z;
    const int nt  = blockIdx.x;

    const size_t wbase = (size_t)bid * 65536;
    const ushort_t* Yblk = Yg + (size_t)bid * 256 * (size_t)Nb + (size_t)nt * NT;

    const int tid  = threadIdx.x;
    const int wave = tid >> 6;
    const int lane = tid & 63;
    const int l16  = lane & 15;
    const int lk   = lane >> 4;             // 0..3

    const int yc = tid & (NT - 1);
    const int yh = tid / NT;                // 0..(256/NT-1)

    f32x4 acc[4][NF];
#pragma unroll
    for (int m = 0; m < 4; ++m)
#pragma unroll
        for (int n = 0; n < NF; ++n)
            acc[m][n] = (f32x4){0.f, 0.f, 0.f, 0.f};

    for (int k0 = 0; k0 < 256; k0 += 32) {
        // ---- global loads ----
        bf16x8 wh[4], wl[4];
        if (PRECONV) {
            const ushort_t* ph = Whi_g + wbase + (size_t)tid * 256 + k0;
            const ushort_t* pl = Wlo_g + wbase + (size_t)tid * 256 + k0;
#pragma unroll
            for (int s = 0; s < 4; ++s) {
                wh[s] = *(const bf16x8*)(ph + 8 * s);
                wl[s] = *(const bf16x8*)(pl + 8 * s);
            }
        } else {
            float4 wv[8];
            const float* wr = Wf + wbase + (size_t)tid * 256 + k0;
#pragma unroll
            for (int s = 0; s < 8; ++s) wv[s] = *(const float4*)(wr + 4 * s);
#pragma unroll
            for (int s = 0; s < 4; ++s) {
                union { bf16x8 v; ushort_t u[8]; } H, L;
                const float* f = (const float*)&wv[2 * s];
#pragma unroll
                for (int e = 0; e < 8; ++e) {
                    const ushort_t h = bf16_rn(f[e]);
                    H.u[e] = h;
                    L.u[e] = bf16_rn(f[e] - bf16_to_f(h));
                }
                wh[s] = H.v;
                wl[s] = L.v;
            }
        }
        ushort_t yhv[KSEG], ylv[KSEG];
#pragma unroll
        for (int j = 0; j < KSEG; ++j) {
            const size_t gi = (size_t)(k0 + yh * KSEG + j) * Nb + yc;
            yhv[j] = Yblk[gi];
            ylv[j] = Yblk[gi + PLANE];
        }

        __syncthreads();   // previous compute phase's LDS reads complete

        // ---- stage to LDS ----
#pragma unroll
        for (int s = 0; s < 4; ++s) {
            *(bf16x8*)&Whi_s[tid * LD + 8 * s] = wh[s];
            *(bf16x8*)&Wlo_s[tid * LD + 8 * s] = wl[s];
        }
#pragma unroll
        for (int s = 0; s < KSEG / 8; ++s) {
            union { bf16x8 v; ushort_t u[8]; } H, L;
#pragma unroll
            for (int e = 0; e < 8; ++e) { H.u[e] = yhv[8 * s + e]; L.u[e] = ylv[8 * s + e]; }
            *(bf16x8*)&Yhi_s[yc * LD + yh * KSEG + 8 * s] = H.v;
            *(bf16x8*)&Ylo_s[yc * LD + yh * KSEG + 8 * s] = L.v;
        }
        __syncthreads();

        // ---- MFMA phase ----
        bf16x8 ahi[4], alo[4];
#pragma unroll
        for (int m = 0; m < 4; ++m) {
            const int row = wave * 64 + m * 16 + l16;
            ahi[m] = *(const bf16x8*)&Whi_s[row * LD + 8 * lk];
            alo[m] = *(const bf16x8*)&Wlo_s[row * LD + 8 * lk];
        }
#pragma unroll
        for (int n = 0; n < NF; ++n) {
            const int col = n * 16 + l16;
            const bf16x8 bhi = *(const bf16x8*)&Yhi_s[col * LD + 8 * lk];
            const bf16x8 blo = *(const bf16x8*)&Ylo_s[col * LD + 8 * lk];
#pragma unroll
            for (int m = 0; m < 4; ++m) {
                acc[m][n] = __builtin_amdgcn_mfma_f32_16x16x32_bf16(ahi[m], bhi, acc[m][n], 0, 0, 0);
                acc[m][n] = __builtin_amdgcn_mfma_f32_16x16x32_bf16(ahi[m], blo, acc[m][n], 0, 0, 0);
                acc[m][n] = __builtin_amdgcn_mfma_f32_16x16x32_bf16(alo[m], bhi, acc[m][n], 0, 0, 0);
            }
        }
    }

    // ---- epilogue: bias + relu + split-bf16 scatter to child blocks ----
    const int gy = bid >> lgG, gx = bid & (G - 1);
    const int NS2 = S2 >> 1;
#pragma unroll
    for (int m = 0; m < 4; ++m) {
#pragma unroll
        for (int r = 0; r < 4; ++r) {
            const int oc = wave * 64 + m * 16 + lk * 4 + r;   // C/D: row=(lane>>4)*4+reg
            const float bi = bias[bid * 256 + oc];
            const int yl = oc >> 7, xl = (oc >> 6) & 1, c = oc & 63;
            const int cy = 2 * gy + yl, cx = 2 * gx + xl;
            const size_t base = (size_t)((cy * (2 * G) + cx) * 64 + c);
#pragma unroll
            for (int n = 0; n < NF; ++n) {
                const float v = fmaxf(acc[m][n][r] + bi, 0.f);
                const int ng = nt * NT + n * 16 + l16;        // C/D: col=lane&15
                size_t flat;
                if (isLast) {
                    flat = base * 64 + (size_t)ng;            // A6[cy][cx][c][b]
                } else {
                    const int b   = ng >> (2 * lgS2);
                    const int rem = ng & ((1 << (2 * lgS2)) - 1);
                    const int p = rem >> lgS2, q = rem & (S2 - 1);
                    flat = ((base * 2 + (p & 1)) * 2 + (q & 1)) * (size_t)(64 * NS2 * NS2)
                         + (size_t)(b * NS2 * NS2 + (p >> 1) * NS2 + (q >> 1));
                }
                const ushort_t h = bf16_rn(v);
                Aout[flat]         = h;
                Aout[flat + PLANE] = bf16_rn(v - bf16_to_f(h));
            }
        }
    }
}

// ---------------- Final layer (scalar, BW-bound) ----------------
__global__ __launch_bounds__(64)
void final_kernel(const ushort_t* __restrict__ A6, const float* __restrict__ wf,
                  const float* __restrict__ bf, float* __restrict__ out) {
    const int blk = blockIdx.x;      // cy*64 + cx
    const int b = threadIdx.x;       // 0..63
    const ushort_t* Y = A6 + (size_t)blk * 4096;
    const float* w0r = wf + (size_t)blk * 256;         // o = 0
    const float* w2r = wf + (size_t)blk * 256 + 128;   // o = 2
    float a0 = 0.f, a2 = 0.f;
#pragma unroll 8
    for (int i = 0; i < 64; ++i) {
        const float y = bf16_to_f(Y[i * 64 + b]) + bf16_to_f(Y[i * 64 + b + PLANE]);
        a0 = fmaf(y, w0r[i], a0);
        a2 = fmaf(y, w2r[i], a2);
    }
    a0 = fmaxf(a0 + bf[blk * 4 + 0], 0.f);
    a2 = fmaxf(a2 + bf[blk * 4 + 2], 0.f);
    const int cy = blk >> 6, cx = blk & 63;
    out[(size_t)b * 4096 + cy * 64 + cx] = (a0 - a2) * (1.0f / 4096.0f);
}

extern "C" void kernel_launch(void* const* d_in, const int* in_sizes, int n_in,
                              void* d_out, int out_size, void* d_ws, size_t ws_size,
                              hipStream_t stream) {
    (void)in_sizes; (void)n_in; (void)out_size; (void)ws_size;

    const float* xr = (const float*)d_in[0];
    const float* xi = (const float*)d_in[1];
    const float* w0 = (const float*)d_in[2];
    const float* b0 = (const float*)d_in[3];
    const float* wrec[5] = { (const float*)d_in[4],  (const float*)d_in[6],
                             (const float*)d_in[8],  (const float*)d_in[10],
                             (const float*)d_in[12] };
    const float* brec[5] = { (const float*)d_in[5],  (const float*)d_in[7],
                             (const float*)d_in[9],  (const float*)d_in[11],
                             (const float*)d_in[13] };
    const float* wf = (const float*)d_in[14];
    const float* bf = (const float*)d_in[15];
    float* out = (float*)d_out;

    ushort_t* base = (ushort_t*)d_ws;
    ushort_t* bufA = base;                         // 2 planes (hi, lo)
    ushort_t* bufB = base + (size_t)2 * PLANE;
    ushort_t* wc1  = base + (size_t)4 * PLANE;     // L1: 262144 elems x2
    ushort_t* wc2  = wc1 + (size_t)2 * 262144;     // L2: 1048576 x2
    ushort_t* wc3  = wc2 + (size_t)2 * 1048576;    // L3: 4194304 x2

    // pre-convert weights for layers 1-3
    wconv_kernel<<<(262144 / 8 + 255) / 256, 256, 0, stream>>>(wrec[0], wc1, wc1 + 262144, 262144 / 8);
    wconv_kernel<<<(1048576 / 8 + 255) / 256, 256, 0, stream>>>(wrec[1], wc2, wc2 + 1048576, 1048576 / 8);
    wconv_kernel<<<(4194304 / 8 + 255) / 256, 256, 0, stream>>>(wrec[2], wc3, wc3 + 4194304, 4194304 / 8);

    layer0_kernel<<<dim3(256, 256), 256, 0, stream>>>(xr, xi, w0, b0, bufA);

    // layer 1: G=2, S2=16, Nb=16384
    rec_mfma_kernel<128, true><<<dim3(128, 1, 4), 256, 0, stream>>>(
        bufA, nullptr, wc1, wc1 + 262144, brec[0], bufB, 1, 4, 0);
    // layer 2: G=4, S2=8, Nb=4096
    rec_mfma_kernel<128, true><<<dim3(32, 1, 16), 256, 0, stream>>>(
        bufB, nullptr, wc2, wc2 + 1048576, brec[1], bufA, 2, 3, 0);
    // layer 3: G=8, S2=4, Nb=1024
    rec_mfma_kernel<128, true><<<dim3(8, 1, 64), 256, 0, stream>>>(
        bufA, nullptr, wc3, wc3 + 4194304, brec[2], bufB, 3, 2, 0);
    // layer 4: G=16, S2=2, Nb=256
    rec_mfma_kernel<128, false><<<dim3(2, 1, 256), 256, 0, stream>>>(
        bufB, wrec[3], nullptr, nullptr, brec[3], bufA, 4, 1, 0);
    // layer 5: G=32, S2=1, Nb=64
    rec_mfma_kernel<64, false><<<dim3(1, 1, 1024), 256, 0, stream>>>(
        bufA, wrec[4], nullptr, nullptr, brec[4], bufB, 5, 0, 1);

    final_kernel<<<4096, 64, 0, stream>>>(bufB, wf, bf, out);
}

// Round 4
// 377.697 us; speedup vs baseline: 1.2726x; 1.2726x over previous
//
#include <hip/hip_runtime.h>
#include <cstddef>

// ButterFlyNet2D IDFT forward. Split-bf16 MFMA (3-pass: Whi*Yhi + Whi*Ylo + Wlo*Yhi).
// Activations between layers: ONE u32 per element = packed (hi bf16 | lo bf16<<16).
//   Same bytes as f32, wide coalesced IO, ~2 bit-ops to deinterleave.
//   Plane layout A[gy][gx][i][k][l][b][p][q] -> per block contiguous Y[256][Nb].
// W pre-converted to bf16 hi/lo planes for layers 1-3; L4/L5 convert in-kernel.
// Rec kernel pipeline: prep -> bar -> stage -> bar -> prefetch(k+1) -> MFMA(k);
// barriers never wait on in-flight prefetch.

typedef unsigned int  u32;
typedef unsigned short u16;
typedef __attribute__((ext_vector_type(8))) short bf16x8;
typedef __attribute__((ext_vector_type(4))) float f32x4;

#define PLANE 16777216   // elements per activation buffer (all layer boundaries)

__device__ inline u16 bf16_rn(float x) {
    u32 u = __builtin_bit_cast(u32, x);
    u32 r = (u + 0x7FFFu + ((u >> 16) & 1u)) >> 16;
    return (u16)r;
}
__device__ inline float bf16_to_f(u16 h) {
    u32 u = ((u32)h) << 16;
    return __builtin_bit_cast(float, u);
}
__device__ inline u32 pack_split(float v) {
    const u16 h = bf16_rn(v);
    const u16 l = bf16_rn(v - bf16_to_f(h));
    return (u32)h | ((u32)l << 16);
}

// ---------------- weight pre-convert (layers 1-3) ----------------
__global__ __launch_bounds__(256)
void wconv_kernel(const float* __restrict__ src, u16* __restrict__ hi,
                  u16* __restrict__ lo, int n8) {
    const int i = blockIdx.x * 256 + threadIdx.x;
    if (i >= n8) return;
    const float4 a = *(const float4*)(src + 8 * i);
    const float4 b = *(const float4*)(src + 8 * i + 4);
    union { bf16x8 v; u16 u[8]; } H, L;
    const float f[8] = {a.x, a.y, a.z, a.w, b.x, b.y, b.z, b.w};
#pragma unroll
    for (int e = 0; e < 8; ++e) {
        const u16 h = bf16_rn(f[e]);
        H.u[e] = h;
        L.u[e] = bf16_rn(f[e] - bf16_to_f(h));
    }
    *(bf16x8*)(hi + 8 * i) = H.v;
    *(bf16x8*)(lo + 8 * i) = L.v;
}

// ---------------- Layer 0 ----------------
// grid (256 pixel-tiles, 16 o-groups); w0 o-slice in LDS; 16 outputs/thread.
__global__ __launch_bounds__(256)
void layer0_kernel(const float* __restrict__ xr, const float* __restrict__ xi,
                   const float* __restrict__ w0, const float* __restrict__ b0,
                   u32* __restrict__ A1) {
    __shared__ float w0s[16][16];
    __shared__ float b0s[16];
    const int og  = blockIdx.y;           // o = og*16 + j
    const int tid = threadIdx.x;
    w0s[tid >> 4][tid & 15] = w0[(og * 16 + (tid >> 4)) * 16 + (tid & 15)];
    if (tid < 16) b0s[tid] = b0[og * 16 + tid];
    __syncthreads();

    const int n = blockIdx.x * 256 + tid;    // pixel: b*1024 + p*32 + q
    const int b = n >> 10, p = (n >> 5) & 31, q = n & 31;
    float xs[16];
#pragma unroll
    for (int k = 0; k < 2; ++k)
#pragma unroll
        for (int l = 0; l < 2; ++l) {
            const int idx = b * 4096 + (2 * p + k) * 64 + (2 * q + l);
            const float vr = xr[idx], vi = xi[idx];
            xs[0  + k * 2 + l] = fmaxf(vr, 0.f);
            xs[4  + k * 2 + l] = fmaxf(vi, 0.f);
            xs[8  + k * 2 + l] = fmaxf(-vr, 0.f);
            xs[12 + k * 2 + l] = fmaxf(-vi, 0.f);
        }
    const int kp = p & 1, lp = q & 1, pp = p >> 1, qp = q >> 1;
    const size_t pixoff = (size_t)(b * 256 + pp * 16 + qp);
#pragma unroll
    for (int j = 0; j < 16; ++j) {
        float acc = b0s[j];
#pragma unroll
        for (int e = 0; e < 16; ++e) acc = fmaf(xs[e], w0s[j][e], acc);
        acc = fmaxf(acc, 0.f);
        const int o = og * 16 + j;
        const int gy = o >> 7, gx = (o >> 6) & 1, c = o & 63;
        const size_t flat = (size_t)((((gy * 2 + gx) * 64 + c) * 2 + kp) * 2 + lp) * (64 * 256)
                          + pixoff;
        A1[flat] = pack_split(acc);
    }
}

// ---------------- Recursion layers 1..5 : split-bf16 MFMA ----------------
template<int NT, bool PRECONV>
__global__ __launch_bounds__(256, 2)
void rec_mfma_kernel(const u32* __restrict__ Yg,
                     const float* __restrict__ Wf,       // f32 W (if !PRECONV)
                     const u16* __restrict__ Whi_g,      // bf16 planes (if PRECONV)
                     const u16* __restrict__ Wlo_g,
                     const float* __restrict__ bias,
                     u32* __restrict__ Aout,
                     const int lgG, const int lgS2, const int isLast) {
    constexpr int NF  = NT / 16;     // B fragments
    constexpr int LD  = 40;          // LDS row stride (shorts); rows 16B-aligned
    constexpr int NCP = NT / 2;      // col-pairs per k-row
    constexpr int NRG = 256 / NCP;   // row groups
    constexpr int RPT = 32 / NRG;    // k-rows per thread (8 or 4)

    __shared__ u16 Whi_s[256 * LD];
    __shared__ u16 Wlo_s[256 * LD];
    __shared__ u16 Yhi_s[NT * LD];
    __shared__ u16 Ylo_s[NT * LD];

    const int G  = 1 << lgG;
    const int S2 = 1 << lgS2;
    const int Nb = 64 << (2 * lgS2);
    const int bid = blockIdx.z;
    const int nt  = blockIdx.x;

    const size_t wbase = (size_t)bid * 65536;
    const u32* Yblk = Yg + (size_t)bid * 256 * (size_t)Nb + (size_t)nt * NT;

    const int tid = threadIdx.x, wave = tid >> 6, lane = tid & 63;
    const int l16 = lane & 15, lk = lane >> 4;

    const int cp   = tid % NCP;
    const int rg   = tid / NCP;
    const int col0 = cp * 2;
    const int trow = rg * RPT;

    f32x4 acc[4][NF];
#pragma unroll
    for (int m = 0; m < 4; ++m)
#pragma unroll
        for (int n = 0; n < NF; ++n)
            acc[m][n] = (f32x4){0.f, 0.f, 0.f, 0.f};

    // staging registers (prefetch target)
    uint2  yreg[RPT];
    float4 wv[8];
    bf16x8 wh[4], wl[4];
    u32 yhw[2][RPT / 2], ylw[2][RPT / 2];

    auto load_regs = [&](int k0) {
        if (PRECONV) {
            const u16* ph = Whi_g + wbase + (size_t)tid * 256 + k0;
            const u16* pl = Wlo_g + wbase + (size_t)tid * 256 + k0;
#pragma unroll
            for (int s = 0; s < 4; ++s) {
                wh[s] = *(const bf16x8*)(ph + 8 * s);
                wl[s] = *(const bf16x8*)(pl + 8 * s);
            }
        } else {
            const float* wr = Wf + wbase + (size_t)tid * 256 + k0;
#pragma unroll
            for (int s = 0; s < 8; ++s) wv[s] = *(const float4*)(wr + 4 * s);
        }
#pragma unroll
        for (int r = 0; r < RPT; ++r)
            yreg[r] = *(const uint2*)(Yblk + (size_t)(k0 + trow + r) * Nb + col0);
    };

    auto prep = [&]() {   // waits on the loads; runs while matrix pipe drains
        if (!PRECONV) {
#pragma unroll
            for (int s = 0; s < 4; ++s) {
                union { bf16x8 v; u16 u[8]; } H, L;
                const float* f = (const float*)&wv[2 * s];
#pragma unroll
                for (int e = 0; e < 8; ++e) {
                    const u16 h = bf16_rn(f[e]);
                    H.u[e] = h;
                    L.u[e] = bf16_rn(f[e] - bf16_to_f(h));
                }
                wh[s] = H.v;
                wl[s] = L.v;
            }
        }
#pragma unroll
        for (int c = 0; c < 2; ++c)
#pragma unroll
            for (int j = 0; j < RPT / 2; ++j) {
                const u32 w0 = c ? yreg[2 * j].y     : yreg[2 * j].x;
                const u32 w1 = c ? yreg[2 * j + 1].y : yreg[2 * j + 1].x;
                yhw[c][j] = (w0 & 0xFFFFu) | (w1 << 16);
                ylw[c][j] = (w0 >> 16)     | (w1 & 0xFFFF0000u);
            }
    };

    auto stage = [&]() {
#pragma unroll
        for (int s = 0; s < 4; ++s) {
            *(bf16x8*)&Whi_s[tid * LD + 8 * s] = wh[s];
            *(bf16x8*)&Wlo_s[tid * LD + 8 * s] = wl[s];
        }
#pragma unroll
        for (int c = 0; c < 2; ++c) {
            if constexpr (RPT == 8) {
                *(uint4*)&Yhi_s[(col0 + c) * LD + trow] = make_uint4(yhw[c][0], yhw[c][1], yhw[c][2], yhw[c][3]);
                *(uint4*)&Ylo_s[(col0 + c) * LD + trow] = make_uint4(ylw[c][0], ylw[c][1], ylw[c][2], ylw[c][3]);
            } else {
                *(uint2*)&Yhi_s[(col0 + c) * LD + trow] = make_uint2(yhw[c][0], yhw[c][1]);
                *(uint2*)&Ylo_s[(col0 + c) * LD + trow] = make_uint2(ylw[c][0], ylw[c][1]);
            }
        }
    };

    load_regs(0);
    for (int k0 = 0; k0 < 256; k0 += 32) {
        prep();
        __syncthreads();     // previous MFMA LDS reads done (no vmem in flight)
        stage();
        __syncthreads();     // LDS visible (no vmem in flight)
        if (k0 + 32 < 256) load_regs(k0 + 32);   // prefetch hides under MFMA
        // ---- MFMA phase ----
        bf16x8 ahi[4], alo[4];
#pragma unroll
        for (int m = 0; m < 4; ++m) {
            const int row = wave * 64 + m * 16 + l16;
            ahi[m] = *(const bf16x8*)&Whi_s[row * LD + 8 * lk];
            alo[m] = *(const bf16x8*)&Wlo_s[row * LD + 8 * lk];
        }
#pragma unroll
        for (int n = 0; n < NF; ++n) {
            const int c = n * 16 + l16;
            const bf16x8 bhi = *(const bf16x8*)&Yhi_s[c * LD + 8 * lk];
            const bf16x8 blo = *(const bf16x8*)&Ylo_s[c * LD + 8 * lk];
#pragma unroll
            for (int m = 0; m < 4; ++m) {
                acc[m][n] = __builtin_amdgcn_mfma_f32_16x16x32_bf16(ahi[m], bhi, acc[m][n], 0, 0, 0);
                acc[m][n] = __builtin_amdgcn_mfma_f32_16x16x32_bf16(ahi[m], blo, acc[m][n], 0, 0, 0);
                acc[m][n] = __builtin_amdgcn_mfma_f32_16x16x32_bf16(alo[m], bhi, acc[m][n], 0, 0, 0);
            }
        }
    }

    // ---- epilogue: bias + relu + packed scatter to child blocks ----
    const int gy = bid >> lgG, gx = bid & (G - 1);
    const int NS2 = S2 >> 1;
#pragma unroll
    for (int m = 0; m < 4; ++m) {
#pragma unroll
        for (int r = 0; r < 4; ++r) {
            const int oc = wave * 64 + m * 16 + lk * 4 + r;   // C/D: row=(lane>>4)*4+reg
            const float bi = bias[(size_t)bid * 256 + oc];
            const int yl = oc >> 7, xl = (oc >> 6) & 1, c = oc & 63;
            const int cy = 2 * gy + yl, cx = 2 * gx + xl;
            const size_t base = (size_t)((cy * (2 * G) + cx) * 64 + c);
#pragma unroll
            for (int n = 0; n < NF; ++n) {
                const float v = fmaxf(acc[m][n][r] + bi, 0.f);
                const int ng = nt * NT + n * 16 + l16;        // C/D: col=lane&15
                size_t flat;
                if (isLast) {
                    flat = base * 64 + (size_t)ng;            // A6[cy][cx][c][b]
                } else {
                    const int b   = ng >> (2 * lgS2);
                    const int rem = ng & ((1 << (2 * lgS2)) - 1);
                    const int p = rem >> lgS2, q = rem & (S2 - 1);
                    flat = ((base * 2 + (p & 1)) * 2 + (q & 1)) * (size_t)(64 * NS2 * NS2)
                         + (size_t)(b * NS2 * NS2 + (p >> 1) * NS2 + (q >> 1));
                }
                Aout[flat] = pack_split(v);
            }
        }
    }
}

// ---------------- Final layer ----------------
__global__ __launch_bounds__(64)
void final_kernel(const u32* __restrict__ A6, const float* __restrict__ wf,
                  const float* __restrict__ bf, float* __restrict__ out) {
    const int blk = blockIdx.x;      // cy*64 + cx
    const int b = threadIdx.x;       // 0..63
    const u32* Y = A6 + (size_t)blk * 4096;
    const float* w0r = wf + (size_t)blk * 256;         // o = 0
    const float* w2r = wf + (size_t)blk * 256 + 128;   // o = 2
    float a0 = 0.f, a2 = 0.f;
#pragma unroll 8
    for (int i = 0; i < 64; ++i) {
        const u32 w = Y[i * 64 + b];
        const float y = bf16_to_f((u16)(w & 0xFFFFu)) + bf16_to_f((u16)(w >> 16));
        a0 = fmaf(y, w0r[i], a0);
        a2 = fmaf(y, w2r[i], a2);
    }
    a0 = fmaxf(a0 + bf[blk * 4 + 0], 0.f);
    a2 = fmaxf(a2 + bf[blk * 4 + 2], 0.f);
    const int cy = blk >> 6, cx = blk & 63;
    out[(size_t)b * 4096 + cy * 64 + cx] = (a0 - a2) * (1.0f / 4096.0f);
}

extern "C" void kernel_launch(void* const* d_in, const int* in_sizes, int n_in,
                              void* d_out, int out_size, void* d_ws, size_t ws_size,
                              hipStream_t stream) {
    (void)in_sizes; (void)n_in; (void)out_size; (void)ws_size;

    const float* xr = (const float*)d_in[0];
    const float* xi = (const float*)d_in[1];
    const float* w0 = (const float*)d_in[2];
    const float* b0 = (const float*)d_in[3];
    const float* wrec[5] = { (const float*)d_in[4],  (const float*)d_in[6],
                             (const float*)d_in[8],  (const float*)d_in[10],
                             (const float*)d_in[12] };
    const float* brec[5] = { (const float*)d_in[5],  (const float*)d_in[7],
                             (const float*)d_in[9],  (const float*)d_in[11],
                             (const float*)d_in[13] };
    const float* wf = (const float*)d_in[14];
    const float* bf = (const float*)d_in[15];
    float* out = (float*)d_out;

    u32* bufA = (u32*)d_ws;
    u32* bufB = bufA + (size_t)PLANE;
    u16* wc1  = (u16*)(bufB + (size_t)PLANE);
    u16* wc2  = wc1 + (size_t)2 * 262144;
    u16* wc3  = wc2 + (size_t)2 * 1048576;

    // pre-convert weights for layers 1-3 (hi/lo planes)
    wconv_kernel<<<(262144 / 8 + 255) / 256, 256, 0, stream>>>(wrec[0], wc1, wc1 + 262144, 262144 / 8);
    wconv_kernel<<<(1048576 / 8 + 255) / 256, 256, 0, stream>>>(wrec[1], wc2, wc2 + 1048576, 1048576 / 8);
    wconv_kernel<<<(4194304 / 8 + 255) / 256, 256, 0, stream>>>(wrec[2], wc3, wc3 + 4194304, 4194304 / 8);

    layer0_kernel<<<dim3(256, 16), 256, 0, stream>>>(xr, xi, w0, b0, bufA);

    // layer 1: G=2, S2=16, Nb=16384
    rec_mfma_kernel<128, true><<<dim3(128, 1, 4), 256, 0, stream>>>(
        bufA, nullptr, wc1, wc1 + 262144, brec[0], bufB, 1, 4, 0);
    // layer 2: G=4, S2=8, Nb=4096
    rec_mfma_kernel<128, true><<<dim3(32, 1, 16), 256, 0, stream>>>(
        bufB, nullptr, wc2, wc2 + 1048576, brec[1], bufA, 2, 3, 0);
    // layer 3: G=8, S2=4, Nb=1024
    rec_mfma_kernel<128, true><<<dim3(8, 1, 64), 256, 0, stream>>>(
        bufA, nullptr, wc3, wc3 + 4194304, brec[2], bufB, 3, 2, 0);
    // layer 4: G=16, S2=2, Nb=256
    rec_mfma_kernel<128, false><<<dim3(2, 1, 256), 256, 0, stream>>>(
        bufB, wrec[3], nullptr, nullptr, brec[3], bufA, 4, 1, 0);
    // layer 5: G=32, S2=1, Nb=64
    rec_mfma_kernel<64, false><<<dim3(1, 1, 1024), 256, 0, stream>>>(
        bufA, wrec[4], nullptr, nullptr, brec[4], bufB, 5, 0, 1);

    final_kernel<<<4096, 64, 0, stream>>>(bufB, wf, bf, out);
}

// Round 5
// 374.714 us; speedup vs baseline: 1.2828x; 1.0080x over previous
//
#include <hip/hip_runtime.h>
#include <cstddef>

// ButterFlyNet2D IDFT forward. Split-bf16 MFMA (3-pass: Whi*Yhi + Whi*Ylo + Wlo*Yhi).
// Activations: ONE u32 per element = packed (hi bf16 | lo bf16<<16).
//   Plane layout A[gy][gx][i][k][l][b][p][q] -> per block contiguous Y[256][Nb].
// W pre-converted to bf16 hi/lo planes for layers 1-3 (L2-resident reuse);
// L4/L5 convert in-kernel. Pipeline: depth-2 register prefetch on the cold
// (HBM) stream, depth-1.5 on the hot stream; setprio around MFMA cluster.
// Final 1x1 layer fused into L5's epilogue (within-wave shfl reduce).

typedef unsigned int  u32;
typedef unsigned short u16;
typedef __attribute__((ext_vector_type(8))) short bf16x8;
typedef __attribute__((ext_vector_type(4))) float f32x4;

#define PLANE 16777216   // elements per activation buffer

__device__ inline u16 bf16_rn(float x) {
    u32 u = __builtin_bit_cast(u32, x);
    u32 r = (u + 0x7FFFu + ((u >> 16) & 1u)) >> 16;
    return (u16)r;
}
__device__ inline float bf16_to_f(u16 h) {
    u32 u = ((u32)h) << 16;
    return __builtin_bit_cast(float, u);
}
__device__ inline u32 pack_split(float v) {
    const u16 h = bf16_rn(v);
    const u16 l = bf16_rn(v - bf16_to_f(h));
    return (u32)h | ((u32)l << 16);
}

// ---------------- weight pre-convert (layers 1-3) ----------------
__global__ __launch_bounds__(256)
void wconv_kernel(const float* __restrict__ src, u16* __restrict__ hi,
                  u16* __restrict__ lo, int n8) {
    const int i = blockIdx.x * 256 + threadIdx.x;
    if (i >= n8) return;
    const float4 a = *(const float4*)(src + 8 * i);
    const float4 b = *(const float4*)(src + 8 * i + 4);
    union { bf16x8 v; u16 u[8]; } H, L;
    const float f[8] = {a.x, a.y, a.z, a.w, b.x, b.y, b.z, b.w};
#pragma unroll
    for (int e = 0; e < 8; ++e) {
        const u16 h = bf16_rn(f[e]);
        H.u[e] = h;
        L.u[e] = bf16_rn(f[e] - bf16_to_f(h));
    }
    *(bf16x8*)(hi + 8 * i) = H.v;
    *(bf16x8*)(lo + 8 * i) = L.v;
}

// ---------------- Layer 0: x read once, 128 outputs per thread ----------------
__global__ __launch_bounds__(256)
void layer0_kernel(const float* __restrict__ xr, const float* __restrict__ xi,
                   const float* __restrict__ w0, const float* __restrict__ b0,
                   u32* __restrict__ A1) {
    __shared__ float w0s[128][16];
    __shared__ float b0s[128];
    const int og  = blockIdx.y;             // 0/1: o = og*128 + j
    const int tid = threadIdx.x;
    {
        const int row = tid >> 1, half = tid & 1;
        const float4 wa = *(const float4*)(w0 + (og * 128 + row) * 16 + half * 8);
        const float4 wb = *(const float4*)(w0 + (og * 128 + row) * 16 + half * 8 + 4);
        *(float4*)&w0s[row][half * 8]     = wa;
        *(float4*)&w0s[row][half * 8 + 4] = wb;
        if (tid < 128) b0s[tid] = b0[og * 128 + tid];
    }
    __syncthreads();

    const int n = blockIdx.x * 256 + tid;   // output pixel: b*1024 + p*32 + q
    const int b = n >> 10, p = (n >> 5) & 31, q = n & 31;
    float xs[16];
#pragma unroll
    for (int k = 0; k < 2; ++k) {
        const float2 vr = *(const float2*)(xr + b * 4096 + (2 * p + k) * 64 + 2 * q);
        const float2 vi = *(const float2*)(xi + b * 4096 + (2 * p + k) * 64 + 2 * q);
        xs[0  + k * 2 + 0] = fmaxf(vr.x, 0.f);  xs[0  + k * 2 + 1] = fmaxf(vr.y, 0.f);
        xs[4  + k * 2 + 0] = fmaxf(vi.x, 0.f);  xs[4  + k * 2 + 1] = fmaxf(vi.y, 0.f);
        xs[8  + k * 2 + 0] = fmaxf(-vr.x, 0.f); xs[8  + k * 2 + 1] = fmaxf(-vr.y, 0.f);
        xs[12 + k * 2 + 0] = fmaxf(-vi.x, 0.f); xs[12 + k * 2 + 1] = fmaxf(-vi.y, 0.f);
    }
    const int kp = p & 1, lp = q & 1, pp = p >> 1, qp = q >> 1;
    const size_t pixoff = (size_t)(b * 256 + pp * 16 + qp);
#pragma unroll
    for (int j = 0; j < 128; ++j) {
        float acc = b0s[j];
#pragma unroll
        for (int e = 0; e < 16; ++e) acc = fmaf(xs[e], w0s[j][e], acc);
        acc = fmaxf(acc, 0.f);
        const int o = og * 128 + j;
        const int gy = o >> 7, gx = (o >> 6) & 1, c = o & 63;
        const size_t flat = (size_t)((((gy * 2 + gx) * 64 + c) * 2 + kp) * 2 + lp) * (64 * 256)
                          + pixoff;
        A1[flat] = pack_split(acc);
    }
}

// ---------------- Recursion layers 1..4 : split-bf16 MFMA ----------------
// PRECONV (L1-3): W from bf16 planes (L2-hot, depth-1.5); Y from HBM (depth-2).
// !PRECONV (L4): W f32 from HBM (depth-2, in-kernel split); Y depth-1.5.
template<int NT, bool PRECONV>
__global__ __launch_bounds__(256, 2)
void rec_mfma_kernel(const u32* __restrict__ Yg,
                     const float* __restrict__ Wf,
                     const u16* __restrict__ Whi_g, const u16* __restrict__ Wlo_g,
                     const float* __restrict__ bias, u32* __restrict__ Aout,
                     const int lgG, const int lgS2) {
    constexpr int NF  = NT / 16;
    constexpr int LD  = 40;
    constexpr int NCP = NT / 2;
    constexpr int NRG = 256 / NCP;
    constexpr int RPT = 32 / NRG;

    __shared__ u16 Whi_s[256 * LD];
    __shared__ u16 Wlo_s[256 * LD];
    __shared__ u16 Yhi_s[NT * LD];
    __shared__ u16 Ylo_s[NT * LD];

    const int G  = 1 << lgG;
    const int S2 = 1 << lgS2;
    const int Nb = 64 << (2 * lgS2);

    // XCD-chunked swizzle: keep all n-tiles of a block on one XCD (W L2 reuse)
    int bid, nt;
    const int nBid = G * G, NTILES = gridDim.x;
    if (nBid >= 8) {
        const int h = blockIdx.z * NTILES + blockIdx.x;
        const int xcd = h & 7, j = h >> 3, per = nBid >> 3;
        bid = xcd * per + j / NTILES;
        nt  = j % NTILES;
    } else { bid = blockIdx.z; nt = blockIdx.x; }

    const size_t wbase = (size_t)bid * 65536;
    const u32* Yblk = Yg + (size_t)bid * 256 * (size_t)Nb + (size_t)nt * NT;

    const int tid = threadIdx.x, wave = tid >> 6, lane = tid & 63;
    const int l16 = lane & 15, lk = lane >> 4;
    const int cp = tid % NCP, rg = tid / NCP;
    const int col0 = cp * 2, trow = rg * RPT;

    f32x4 acc[4][NF];
#pragma unroll
    for (int m = 0; m < 4; ++m)
#pragma unroll
        for (int n = 0; n < NF; ++n)
            acc[m][n] = (f32x4){0.f, 0.f, 0.f, 0.f};

    uint2  yreg[2][RPT];
    float4 wv[2][8];
    bf16x8 wh[4], wl[4];
    u32 yhw[2][RPT / 2], ylw[2][RPT / 2];

    auto loadY = [&](int ybuf, int k0) {
#pragma unroll
        for (int r = 0; r < RPT; ++r)
            yreg[ybuf][r] = *(const uint2*)(Yblk + (size_t)(k0 + trow + r) * Nb + col0);
    };
    auto loadWpre = [&](int k0) {
        const u16* ph = Whi_g + wbase + (size_t)tid * 256 + k0;
        const u16* pl = Wlo_g + wbase + (size_t)tid * 256 + k0;
#pragma unroll
        for (int s = 0; s < 4; ++s) {
            wh[s] = *(const bf16x8*)(ph + 8 * s);
            wl[s] = *(const bf16x8*)(pl + 8 * s);
        }
    };
    auto loadWf32 = [&](int wbuf, int k0) {
        const float* wr = Wf + wbase + (size_t)tid * 256 + k0;
#pragma unroll
        for (int s = 0; s < 8; ++s) wv[wbuf][s] = *(const float4*)(wr + 4 * s);
    };

    if constexpr (PRECONV) { loadY(0, 0); loadY(1, 32); loadWpre(0); }
    else                   { loadWf32(0, 0); loadWf32(1, 32); loadY(0, 0); }

#pragma unroll
    for (int it = 0; it < 8; ++it) {
        const int k0 = it * 32;
        const int cur = it & 1;
        // ---- prep (waits on loads; W convert for f32 path) ----
        if constexpr (!PRECONV) {
#pragma unroll
            for (int s = 0; s < 4; ++s) {
                union { bf16x8 v; u16 u[8]; } H, L;
                const float* f = (const float*)&wv[cur][2 * s];
#pragma unroll
                for (int e = 0; e < 8; ++e) {
                    const u16 hh = bf16_rn(f[e]);
                    H.u[e] = hh;
                    L.u[e] = bf16_rn(f[e] - bf16_to_f(hh));
                }
                wh[s] = H.v;
                wl[s] = L.v;
            }
        }
        {
            const int ybuf = PRECONV ? cur : 0;
#pragma unroll
            for (int c = 0; c < 2; ++c)
#pragma unroll
                for (int j2 = 0; j2 < RPT / 2; ++j2) {
                    const u32 a = c ? yreg[ybuf][2 * j2].y     : yreg[ybuf][2 * j2].x;
                    const u32 b = c ? yreg[ybuf][2 * j2 + 1].y : yreg[ybuf][2 * j2 + 1].x;
                    yhw[c][j2] = (a & 0xFFFFu) | (b << 16);
                    ylw[c][j2] = (a >> 16)     | (b & 0xFFFF0000u);
                }
        }
        __syncthreads();
        // ---- stage ----
#pragma unroll
        for (int s = 0; s < 4; ++s) {
            *(bf16x8*)&Whi_s[tid * LD + 8 * s] = wh[s];
            *(bf16x8*)&Wlo_s[tid * LD + 8 * s] = wl[s];
        }
#pragma unroll
        for (int c = 0; c < 2; ++c) {
            if constexpr (RPT == 8) {
                *(uint4*)&Yhi_s[(col0 + c) * LD + trow] = make_uint4(yhw[c][0], yhw[c][1], yhw[c][2], yhw[c][3]);
                *(uint4*)&Ylo_s[(col0 + c) * LD + trow] = make_uint4(ylw[c][0], ylw[c][1], ylw[c][2], ylw[c][3]);
            } else {
                *(uint2*)&Yhi_s[(col0 + c) * LD + trow] = make_uint2(yhw[c][0], yhw[c][1]);
                *(uint2*)&Ylo_s[(col0 + c) * LD + trow] = make_uint2(ylw[c][0], ylw[c][1]);
            }
        }
        __syncthreads();
        // ---- prefetch (depth-2 cold stream, depth-1.5 hot stream) ----
        if constexpr (PRECONV) {
            if (it + 2 < 8) loadY(cur, k0 + 64);
            if (it + 1 < 8) loadWpre(k0 + 32);
        } else {
            if (it + 2 < 8) loadWf32(cur, k0 + 64);
            if (it + 1 < 8) loadY(0, k0 + 32);
        }
        // ---- MFMA ----
        __builtin_amdgcn_s_setprio(1);
        bf16x8 ahi[4], alo[4];
#pragma unroll
        for (int m = 0; m < 4; ++m) {
            const int row = wave * 64 + m * 16 + l16;
            ahi[m] = *(const bf16x8*)&Whi_s[row * LD + 8 * lk];
            alo[m] = *(const bf16x8*)&Wlo_s[row * LD + 8 * lk];
        }
#pragma unroll
        for (int n = 0; n < NF; ++n) {
            const int ccol = n * 16 + l16;
            const bf16x8 bhi = *(const bf16x8*)&Yhi_s[ccol * LD + 8 * lk];
            const bf16x8 blo = *(const bf16x8*)&Ylo_s[ccol * LD + 8 * lk];
#pragma unroll
            for (int m = 0; m < 4; ++m) {
                acc[m][n] = __builtin_amdgcn_mfma_f32_16x16x32_bf16(ahi[m], bhi, acc[m][n], 0, 0, 0);
                acc[m][n] = __builtin_amdgcn_mfma_f32_16x16x32_bf16(ahi[m], blo, acc[m][n], 0, 0, 0);
                acc[m][n] = __builtin_amdgcn_mfma_f32_16x16x32_bf16(alo[m], bhi, acc[m][n], 0, 0, 0);
            }
        }
        __builtin_amdgcn_s_setprio(0);
    }

    // ---- epilogue: bias + relu + packed scatter to child blocks ----
    const int gy = bid >> lgG, gx = bid & (G - 1);
    const int NS2 = S2 >> 1;
#pragma unroll
    for (int m = 0; m < 4; ++m) {
#pragma unroll
        for (int r = 0; r < 4; ++r) {
            const int oc = wave * 64 + m * 16 + lk * 4 + r;   // C/D: row=(lane>>4)*4+reg
            const float bi = bias[(size_t)bid * 256 + oc];
            const int yl = oc >> 7, xl = (oc >> 6) & 1, cch = oc & 63;
            const int cy = 2 * gy + yl, cx = 2 * gx + xl;
            const size_t base = (size_t)((cy * (2 * G) + cx) * 64 + cch);
#pragma unroll
            for (int n = 0; n < NF; ++n) {
                const float v = fmaxf(acc[m][n][r] + bi, 0.f);
                const int ng = nt * NT + n * 16 + l16;        // C/D: col=lane&15
                const int b   = ng >> (2 * lgS2);
                const int rem = ng & ((1 << (2 * lgS2)) - 1);
                const int p = rem >> lgS2, q = rem & (S2 - 1);
                const size_t flat = ((base * 2 + (p & 1)) * 2 + (q & 1)) * (size_t)(64 * NS2 * NS2)
                                  + (size_t)(b * NS2 * NS2 + (p >> 1) * NS2 + (q >> 1));
                Aout[flat] = pack_split(v);
            }
        }
    }
}

// ---------------- Layer 5 + final, fused ----------------
// NT=64: wave w owns child block (2gy+(w>>1), 2gx+(w&1)), all 64 ch x 64 batch.
__global__ __launch_bounds__(256, 2)
void rec5_final_kernel(const u32* __restrict__ Yg, const float* __restrict__ Wf,
                       const float* __restrict__ bias, const float* __restrict__ wf,
                       const float* __restrict__ bff, float* __restrict__ out) {
    constexpr int NF = 4, LD = 40, RPT = 4;   // NT=64, NCP=32, NRG=8

    __shared__ u16 Whi_s[256 * LD];
    __shared__ u16 Wlo_s[256 * LD];
    __shared__ u16 Yhi_s[64 * LD];
    __shared__ u16 Ylo_s[64 * LD];

    const int bid = blockIdx.x;               // 0..1023 (G=32)
    const size_t wbase = (size_t)bid * 65536;
    const u32* Yblk = Yg + (size_t)bid * 256 * 64;

    const int tid = threadIdx.x, wave = tid >> 6, lane = tid & 63;
    const int l16 = lane & 15, lk = lane >> 4;
    const int cp = tid & 31, rg = tid >> 5;
    const int col0 = cp * 2, trow = rg * RPT;

    f32x4 acc[4][NF];
#pragma unroll
    for (int m = 0; m < 4; ++m)
#pragma unroll
        for (int n = 0; n < NF; ++n)
            acc[m][n] = (f32x4){0.f, 0.f, 0.f, 0.f};

    uint2  yreg[RPT];
    float4 wv[2][8];
    bf16x8 wh[4], wl[4];
    u32 yhw[2][RPT / 2], ylw[2][RPT / 2];

    auto loadY = [&](int k0) {
#pragma unroll
        for (int r = 0; r < RPT; ++r)
            yreg[r] = *(const uint2*)(Yblk + (size_t)(k0 + trow + r) * 64 + col0);
    };
    auto loadWf32 = [&](int wbuf, int k0) {
        const float* wr = Wf + wbase + (size_t)tid * 256 + k0;
#pragma unroll
        for (int s = 0; s < 8; ++s) wv[wbuf][s] = *(const float4*)(wr + 4 * s);
    };

    loadWf32(0, 0); loadWf32(1, 32); loadY(0);

#pragma unroll
    for (int it = 0; it < 8; ++it) {
        const int k0 = it * 32;
        const int cur = it & 1;
#pragma unroll
        for (int s = 0; s < 4; ++s) {
            union { bf16x8 v; u16 u[8]; } H, L;
            const float* f = (const float*)&wv[cur][2 * s];
#pragma unroll
            for (int e = 0; e < 8; ++e) {
                const u16 hh = bf16_rn(f[e]);
                H.u[e] = hh;
                L.u[e] = bf16_rn(f[e] - bf16_to_f(hh));
            }
            wh[s] = H.v;
            wl[s] = L.v;
        }
#pragma unroll
        for (int c = 0; c < 2; ++c)
#pragma unroll
            for (int j2 = 0; j2 < RPT / 2; ++j2) {
                const u32 a = c ? yreg[2 * j2].y     : yreg[2 * j2].x;
                const u32 b = c ? yreg[2 * j2 + 1].y : yreg[2 * j2 + 1].x;
                yhw[c][j2] = (a & 0xFFFFu) | (b << 16);
                ylw[c][j2] = (a >> 16)     | (b & 0xFFFF0000u);
            }
        __syncthreads();
#pragma unroll
        for (int s = 0; s < 4; ++s) {
            *(bf16x8*)&Whi_s[tid * LD + 8 * s] = wh[s];
            *(bf16x8*)&Wlo_s[tid * LD + 8 * s] = wl[s];
        }
#pragma unroll
        for (int c = 0; c < 2; ++c) {
            *(uint2*)&Yhi_s[(col0 + c) * LD + trow] = make_uint2(yhw[c][0], yhw[c][1]);
            *(uint2*)&Ylo_s[(col0 + c) * LD + trow] = make_uint2(ylw[c][0], ylw[c][1]);
        }
        __syncthreads();
        if (it + 2 < 8) loadWf32(cur, k0 + 64);
        if (it + 1 < 8) loadY(k0 + 32);
        __builtin_amdgcn_s_setprio(1);
        bf16x8 ahi[4], alo[4];
#pragma unroll
        for (int m = 0; m < 4; ++m) {
            const int row = wave * 64 + m * 16 + l16;
            ahi[m] = *(const bf16x8*)&Whi_s[row * LD + 8 * lk];
            alo[m] = *(const bf16x8*)&Wlo_s[row * LD + 8 * lk];
        }
#pragma unroll
        for (int n = 0; n < NF; ++n) {
            const int ccol = n * 16 + l16;
            const bf16x8 bhi = *(const bf16x8*)&Yhi_s[ccol * LD + 8 * lk];
            const bf16x8 blo = *(const bf16x8*)&Ylo_s[ccol * LD + 8 * lk];
#pragma unroll
            for (int m = 0; m < 4; ++m) {
                acc[m][n] = __builtin_amdgcn_mfma_f32_16x16x32_bf16(ahi[m], bhi, acc[m][n], 0, 0, 0);
                acc[m][n] = __builtin_amdgcn_mfma_f32_16x16x32_bf16(ahi[m], blo, acc[m][n], 0, 0, 0);
                acc[m][n] = __builtin_amdgcn_mfma_f32_16x16x32_bf16(alo[m], bhi, acc[m][n], 0, 0, 0);
            }
        }
        __builtin_amdgcn_s_setprio(0);
    }

    // ---- fused final: per-wave child block, within-wave reduce over channels ----
    const int gy = bid >> 5, gx = bid & 31;
    const int cy = 2 * gy + (wave >> 1), cx = 2 * gx + (wave & 1);
    const int blk = cy * 64 + cx;
    float wf0v[4][4], wf2v[4][4], biv[4][4];
#pragma unroll
    for (int m = 0; m < 4; ++m)
#pragma unroll
        for (int r = 0; r < 4; ++r) {
            const int cch = m * 16 + lk * 4 + r;
            wf0v[m][r] = wf[(size_t)blk * 256 + cch];
            wf2v[m][r] = wf[(size_t)blk * 256 + 128 + cch];
            biv[m][r]  = bias[(size_t)bid * 256 + wave * 64 + cch];
        }
    const float bf0 = bff[blk * 4 + 0], bf2 = bff[blk * 4 + 2];
#pragma unroll
    for (int n = 0; n < 4; ++n) {
        float a0 = 0.f, a2 = 0.f;
#pragma unroll
        for (int m = 0; m < 4; ++m)
#pragma unroll
            for (int r = 0; r < 4; ++r) {
                const float y = fmaxf(acc[m][n][r] + biv[m][r], 0.f);
                a0 = fmaf(y, wf0v[m][r], a0);
                a2 = fmaf(y, wf2v[m][r], a2);
            }
        a0 += __shfl_xor(a0, 16); a0 += __shfl_xor(a0, 32);
        a2 += __shfl_xor(a2, 16); a2 += __shfl_xor(a2, 32);
        if (lk == n) {
            const float o0 = fmaxf(a0 + bf0, 0.f);
            const float o2 = fmaxf(a2 + bf2, 0.f);
            out[(size_t)(n * 16 + l16) * 4096 + blk] = (o0 - o2) * (1.0f / 4096.0f);
        }
    }
}

extern "C" void kernel_launch(void* const* d_in, const int* in_sizes, int n_in,
                              void* d_out, int out_size, void* d_ws, size_t ws_size,
                              hipStream_t stream) {
    (void)in_sizes; (void)n_in; (void)out_size; (void)ws_size;

    const float* xr = (const float*)d_in[0];
    const float* xi = (const float*)d_in[1];
    const float* w0 = (const float*)d_in[2];
    const float* b0 = (const float*)d_in[3];
    const float* wrec[5] = { (const float*)d_in[4],  (const float*)d_in[6],
                             (const float*)d_in[8],  (const float*)d_in[10],
                             (const float*)d_in[12] };
    const float* brec[5] = { (const float*)d_in[5],  (const float*)d_in[7],
                             (const float*)d_in[9],  (const float*)d_in[11],
                             (const float*)d_in[13] };
    const float* wf = (const float*)d_in[14];
    const float* bf = (const float*)d_in[15];
    float* out = (float*)d_out;

    u32* bufA = (u32*)d_ws;
    u32* bufB = bufA + (size_t)PLANE;
    u16* wc1  = (u16*)(bufB + (size_t)PLANE);
    u16* wc2  = wc1 + (size_t)2 * 262144;
    u16* wc3  = wc2 + (size_t)2 * 1048576;

    wconv_kernel<<<(262144 / 8 + 255) / 256, 256, 0, stream>>>(wrec[0], wc1, wc1 + 262144, 262144 / 8);
    wconv_kernel<<<(1048576 / 8 + 255) / 256, 256, 0, stream>>>(wrec[1], wc2, wc2 + 1048576, 1048576 / 8);
    wconv_kernel<<<(4194304 / 8 + 255) / 256, 256, 0, stream>>>(wrec[2], wc3, wc3 + 4194304, 4194304 / 8);

    layer0_kernel<<<dim3(256, 2), 256, 0, stream>>>(xr, xi, w0, b0, bufA);

    // layer 1: G=2,  S2=16, Nb=16384
    rec_mfma_kernel<128, true><<<dim3(128, 1, 4), 256, 0, stream>>>(
        bufA, nullptr, wc1, wc1 + 262144, brec[0], bufB, 1, 4);
    // layer 2: G=4,  S2=8,  Nb=4096
    rec_mfma_kernel<128, true><<<dim3(32, 1, 16), 256, 0, stream>>>(
        bufB, nullptr, wc2, wc2 + 1048576, brec[1], bufA, 2, 3);
    // layer 3: G=8,  S2=4,  Nb=1024
    rec_mfma_kernel<128, true><<<dim3(8, 1, 64), 256, 0, stream>>>(
        bufA, nullptr, wc3, wc3 + 4194304, brec[2], bufB, 3, 2);
    // layer 4: G=16, S2=2,  Nb=256 (NT=64 -> 4 n-tiles)
    rec_mfma_kernel<64, false><<<dim3(4, 1, 256), 256, 0, stream>>>(
        bufB, wrec[3], nullptr, nullptr, brec[3], bufA, 4, 1);
    // layer 5 + final fused: G=32, Nb=64
    rec5_final_kernel<<<1024, 256, 0, stream>>>(bufA, wrec[4], brec[4], wf, bf, out);
}

// Round 6
// 320.142 us; speedup vs baseline: 1.5014x; 1.1705x over previous
//
#include <hip/hip_runtime.h>
#include <cstddef>

// ButterFlyNet2D IDFT forward. Split-bf16 MFMA (3-pass: Whi*Yhi + Whi*Ylo + Wlo*Yhi).
// Activations: ONE u32 per element = packed (hi bf16 | lo bf16<<16).
//   Plane layout A[gy][gx][i][k][l][b][p][q] -> per block contiguous Y[256][Nb].
// R6: W bypasses LDS entirely (direct global->register MFMA A-fragments; each
// wave owns its 64 rows). LDS holds only the Y tile. GEMM-loop barriers are raw
// "s_waitcnt lgkmcnt(0); s_barrier" so in-flight global loads (vmcnt) are NEVER
// drained at barriers -> true cross-iteration prefetch. MFMA pass-outer order.

typedef unsigned int  u32;
typedef unsigned short u16;
typedef __attribute__((ext_vector_type(8))) short bf16x8;
typedef __attribute__((ext_vector_type(4))) float f32x4;

#define PLANE 16777216   // elements per activation buffer

__device__ inline u16 bf16_rn(float x) {
    u32 u = __builtin_bit_cast(u32, x);
    u32 r = (u + 0x7FFFu + ((u >> 16) & 1u)) >> 16;
    return (u16)r;
}
__device__ inline float bf16_to_f(u16 h) {
    u32 u = ((u32)h) << 16;
    return __builtin_bit_cast(float, u);
}
__device__ inline u32 pack_split(float v) {
    const u16 h = bf16_rn(v);
    const u16 l = bf16_rn(v - bf16_to_f(h));
    return (u32)h | ((u32)l << 16);
}
// LDS-only barrier: drains ds ops, leaves global loads (vmcnt) in flight.
__device__ inline void bar_lds() {
    asm volatile("s_waitcnt lgkmcnt(0)\n\ts_barrier" ::: "memory");
}

// ---------------- weight pre-convert (layers 1-3) ----------------
__global__ __launch_bounds__(256)
void wconv_kernel(const float* __restrict__ src, u16* __restrict__ hi,
                  u16* __restrict__ lo, int n8) {
    const int i = blockIdx.x * 256 + threadIdx.x;
    if (i >= n8) return;
    const float4 a = *(const float4*)(src + 8 * i);
    const float4 b = *(const float4*)(src + 8 * i + 4);
    union { bf16x8 v; u16 u[8]; } H, L;
    const float f[8] = {a.x, a.y, a.z, a.w, b.x, b.y, b.z, b.w};
#pragma unroll
    for (int e = 0; e < 8; ++e) {
        const u16 h = bf16_rn(f[e]);
        H.u[e] = h;
        L.u[e] = bf16_rn(f[e] - bf16_to_f(h));
    }
    *(bf16x8*)(hi + 8 * i) = H.v;
    *(bf16x8*)(lo + 8 * i) = L.v;
}

// ---------------- Layer 0: x read once, 128 outputs per thread ----------------
__global__ __launch_bounds__(256)
void layer0_kernel(const float* __restrict__ xr, const float* __restrict__ xi,
                   const float* __restrict__ w0, const float* __restrict__ b0,
                   u32* __restrict__ A1) {
    __shared__ float w0s[128][16];
    __shared__ float b0s[128];
    const int og  = blockIdx.y;             // 0/1: o = og*128 + j
    const int tid = threadIdx.x;
    {
        const int row = tid >> 1, half = tid & 1;
        const float4 wa = *(const float4*)(w0 + (og * 128 + row) * 16 + half * 8);
        const float4 wb = *(const float4*)(w0 + (og * 128 + row) * 16 + half * 8 + 4);
        *(float4*)&w0s[row][half * 8]     = wa;
        *(float4*)&w0s[row][half * 8 + 4] = wb;
        if (tid < 128) b0s[tid] = b0[og * 128 + tid];
    }
    __syncthreads();

    const int n = blockIdx.x * 256 + tid;   // output pixel: b*1024 + p*32 + q
    const int b = n >> 10, p = (n >> 5) & 31, q = n & 31;
    float xs[16];
#pragma unroll
    for (int k = 0; k < 2; ++k) {
        const float2 vr = *(const float2*)(xr + b * 4096 + (2 * p + k) * 64 + 2 * q);
        const float2 vi = *(const float2*)(xi + b * 4096 + (2 * p + k) * 64 + 2 * q);
        xs[0  + k * 2 + 0] = fmaxf(vr.x, 0.f);  xs[0  + k * 2 + 1] = fmaxf(vr.y, 0.f);
        xs[4  + k * 2 + 0] = fmaxf(vi.x, 0.f);  xs[4  + k * 2 + 1] = fmaxf(vi.y, 0.f);
        xs[8  + k * 2 + 0] = fmaxf(-vr.x, 0.f); xs[8  + k * 2 + 1] = fmaxf(-vr.y, 0.f);
        xs[12 + k * 2 + 0] = fmaxf(-vi.x, 0.f); xs[12 + k * 2 + 1] = fmaxf(-vi.y, 0.f);
    }
    const int kp = p & 1, lp = q & 1, pp = p >> 1, qp = q >> 1;
    const size_t pixoff = (size_t)(b * 256 + pp * 16 + qp);
#pragma unroll
    for (int j = 0; j < 128; ++j) {
        float acc = b0s[j];
#pragma unroll
        for (int e = 0; e < 16; ++e) acc = fmaf(xs[e], w0s[j][e], acc);
        acc = fmaxf(acc, 0.f);
        const int o = og * 128 + j;
        const int gy = o >> 7, gx = (o >> 6) & 1, c = o & 63;
        const size_t flat = (size_t)((((gy * 2 + gx) * 64 + c) * 2 + kp) * 2 + lp) * (64 * 256)
                          + pixoff;
        A1[flat] = pack_split(acc);
    }
}

// ---------------- Recursion layers 1..4 : split-bf16 MFMA, W direct ----------------
template<int NT, bool PRECONV>
__global__ __launch_bounds__(256, 2)
void rec_mfma_kernel(const u32* __restrict__ Yg,
                     const float* __restrict__ Wf,
                     const u16* __restrict__ Whi_g, const u16* __restrict__ Wlo_g,
                     const float* __restrict__ bias, u32* __restrict__ Aout,
                     const int lgG, const int lgS2) {
    constexpr int NF  = NT / 16;
    constexpr int LD  = 40;
    constexpr int NCP = NT / 2;
    constexpr int NRG = 256 / NCP;
    constexpr int RPT = 32 / NRG;

    __shared__ u16 Yhi_s[NT * LD];
    __shared__ u16 Ylo_s[NT * LD];

    const int G  = 1 << lgG;
    const int S2 = 1 << lgS2;
    const int Nb = 64 << (2 * lgS2);

    // XCD-chunked swizzle: keep all n-tiles of a block on one XCD (W L2 reuse)
    int bid, nt;
    const int nBid = G * G, NTILES = gridDim.x;
    if (nBid >= 8) {
        const int h = blockIdx.z * NTILES + blockIdx.x;
        const int xcd = h & 7, j = h >> 3, per = nBid >> 3;
        bid = xcd * per + j / NTILES;
        nt  = j % NTILES;
    } else { bid = blockIdx.z; nt = blockIdx.x; }

    const size_t wbase = (size_t)bid * 65536;
    const u32* Yblk = Yg + (size_t)bid * 256 * (size_t)Nb + (size_t)nt * NT;

    const int tid = threadIdx.x, wave = tid >> 6, lane = tid & 63;
    const int l16 = lane & 15, lk = lane >> 4;
    const int cp = tid % NCP, rg = tid / NCP;
    const int col0 = cp * 2, trow = rg * RPT;

    f32x4 acc[4][NF];
#pragma unroll
    for (int m = 0; m < 4; ++m)
#pragma unroll
        for (int n = 0; n < NF; ++n)
            acc[m][n] = (f32x4){0.f, 0.f, 0.f, 0.f};

    uint2  yreg[2][RPT];
    float4 wv[2][8];         // f32 path staging (double-buffered)
    bf16x8 wh[4], wl[4];     // A-fragments for the current iter
    u32 yhw[2][RPT / 2], ylw[2][RPT / 2];

    auto loadY = [&](int ybuf, int k0) {
#pragma unroll
        for (int r = 0; r < RPT; ++r)
            yreg[ybuf][r] = *(const uint2*)(Yblk + (size_t)(k0 + trow + r) * Nb + col0);
    };
    auto loadWpre = [&](int k0) {   // direct bf16 fragment loads (L2-hot)
#pragma unroll
        for (int m = 0; m < 4; ++m) {
            const size_t off = wbase + (size_t)(wave * 64 + m * 16 + l16) * 256 + k0 + lk * 8;
            wh[m] = *(const bf16x8*)(Whi_g + off);
            wl[m] = *(const bf16x8*)(Wlo_g + off);
        }
    };
    auto loadWf32 = [&](int wbuf, int k0) {
#pragma unroll
        for (int m = 0; m < 4; ++m) {
            const float* wr = Wf + wbase + (size_t)(wave * 64 + m * 16 + l16) * 256 + k0 + lk * 8;
            wv[wbuf][2 * m]     = *(const float4*)wr;
            wv[wbuf][2 * m + 1] = *(const float4*)(wr + 4);
        }
    };
    auto convW = [&](int wbuf) {
#pragma unroll
        for (int m = 0; m < 4; ++m) {
            const float f[8] = { wv[wbuf][2 * m].x,     wv[wbuf][2 * m].y,
                                 wv[wbuf][2 * m].z,     wv[wbuf][2 * m].w,
                                 wv[wbuf][2 * m + 1].x, wv[wbuf][2 * m + 1].y,
                                 wv[wbuf][2 * m + 1].z, wv[wbuf][2 * m + 1].w };
            union { bf16x8 v; u16 u[8]; } H, L;
#pragma unroll
            for (int e = 0; e < 8; ++e) {
                const u16 hh = bf16_rn(f[e]);
                H.u[e] = hh;
                L.u[e] = bf16_rn(f[e] - bf16_to_f(hh));
            }
            wh[m] = H.v;
            wl[m] = L.v;
        }
    };
    auto prepY = [&](int ybuf) {
#pragma unroll
        for (int c = 0; c < 2; ++c)
#pragma unroll
            for (int j2 = 0; j2 < RPT / 2; ++j2) {
                const u32 a = c ? yreg[ybuf][2 * j2].y     : yreg[ybuf][2 * j2].x;
                const u32 b = c ? yreg[ybuf][2 * j2 + 1].y : yreg[ybuf][2 * j2 + 1].x;
                yhw[c][j2] = (a & 0xFFFFu) | (b << 16);
                ylw[c][j2] = (a >> 16)     | (b & 0xFFFF0000u);
            }
    };
    auto stageY = [&]() {
#pragma unroll
        for (int c = 0; c < 2; ++c) {
            if constexpr (RPT == 8) {
                *(uint4*)&Yhi_s[(col0 + c) * LD + trow] = make_uint4(yhw[c][0], yhw[c][1], yhw[c][2], yhw[c][3]);
                *(uint4*)&Ylo_s[(col0 + c) * LD + trow] = make_uint4(ylw[c][0], ylw[c][1], ylw[c][2], ylw[c][3]);
            } else {
                *(uint2*)&Yhi_s[(col0 + c) * LD + trow] = make_uint2(yhw[c][0], yhw[c][1]);
                *(uint2*)&Ylo_s[(col0 + c) * LD + trow] = make_uint2(ylw[c][0], ylw[c][1]);
            }
        }
    };

    if constexpr (PRECONV) { loadY(0, 0); loadY(1, 32); }
    else { loadWf32(0, 0); loadY(0, 0); loadWf32(1, 32); loadY(1, 32); }

#pragma unroll
    for (int it = 0; it < 8; ++it) {
        const int k0 = it * 32;
        const int cur = it & 1;
        if constexpr (PRECONV) loadWpre(k0);   // in flight across barriers (no vmcnt drain)
        else convW(cur);                        // waits on wv[cur] (issued >=1 iter ago)
        prepY(cur);                             // waits on yreg[cur] (issued 2 iters ago)
        bar_lds();                              // prev MFMA ds_reads done; LDS reusable
        stageY();
        bar_lds();                              // Y tile visible
        if constexpr (PRECONV) {
            if (it + 2 < 8) loadY(cur, k0 + 64);
        } else {
            if (it + 2 < 8) { loadWf32(cur, k0 + 64); loadY(cur, k0 + 64); }
        }
        __builtin_amdgcn_s_setprio(1);
#pragma unroll
        for (int n = 0; n < NF; ++n) {
            const int ccol = n * 16 + l16;
            const bf16x8 bhi = *(const bf16x8*)&Yhi_s[ccol * LD + 8 * lk];
            const bf16x8 blo = *(const bf16x8*)&Ylo_s[ccol * LD + 8 * lk];
#pragma unroll
            for (int m = 0; m < 4; ++m)
                acc[m][n] = __builtin_amdgcn_mfma_f32_16x16x32_bf16(wh[m], bhi, acc[m][n], 0, 0, 0);
#pragma unroll
            for (int m = 0; m < 4; ++m)
                acc[m][n] = __builtin_amdgcn_mfma_f32_16x16x32_bf16(wh[m], blo, acc[m][n], 0, 0, 0);
#pragma unroll
            for (int m = 0; m < 4; ++m)
                acc[m][n] = __builtin_amdgcn_mfma_f32_16x16x32_bf16(wl[m], bhi, acc[m][n], 0, 0, 0);
        }
        __builtin_amdgcn_s_setprio(0);
    }

    // ---- epilogue: bias + relu + packed scatter to child blocks ----
    const int gy = bid >> lgG, gx = bid & (G - 1);
    const int NS2 = S2 >> 1;
#pragma unroll
    for (int m = 0; m < 4; ++m) {
#pragma unroll
        for (int r = 0; r < 4; ++r) {
            const int oc = wave * 64 + m * 16 + lk * 4 + r;   // C/D: row=(lane>>4)*4+reg
            const float bi = bias[(size_t)bid * 256 + oc];
            const int yl = oc >> 7, xl = (oc >> 6) & 1, cch = oc & 63;
            const int cy = 2 * gy + yl, cx = 2 * gx + xl;
            const size_t base = (size_t)((cy * (2 * G) + cx) * 64 + cch);
#pragma unroll
            for (int n = 0; n < NF; ++n) {
                const float v = fmaxf(acc[m][n][r] + bi, 0.f);
                const int ng = nt * NT + n * 16 + l16;        // C/D: col=lane&15
                const int b   = ng >> (2 * lgS2);
                const int rem = ng & ((1 << (2 * lgS2)) - 1);
                const int p = rem >> lgS2, q = rem & (S2 - 1);
                const size_t flat = ((base * 2 + (p & 1)) * 2 + (q & 1)) * (size_t)(64 * NS2 * NS2)
                                  + (size_t)(b * NS2 * NS2 + (p >> 1) * NS2 + (q >> 1));
                Aout[flat] = pack_split(v);
            }
        }
    }
}

// ---------------- Layer 5 + final, fused (W direct) ----------------
__global__ __launch_bounds__(256, 2)
void rec5_final_kernel(const u32* __restrict__ Yg, const float* __restrict__ Wf,
                       const float* __restrict__ bias, const float* __restrict__ wf,
                       const float* __restrict__ bff, float* __restrict__ out) {
    constexpr int NF = 4, LD = 40, RPT = 4;   // NT=64, NCP=32, NRG=8

    __shared__ u16 Yhi_s[64 * LD];
    __shared__ u16 Ylo_s[64 * LD];

    const int bid = blockIdx.x;               // 0..1023 (G=32)
    const size_t wbase = (size_t)bid * 65536;
    const u32* Yblk = Yg + (size_t)bid * 256 * 64;

    const int tid = threadIdx.x, wave = tid >> 6, lane = tid & 63;
    const int l16 = lane & 15, lk = lane >> 4;
    const int cp = tid & 31, rg = tid >> 5;
    const int col0 = cp * 2, trow = rg * RPT;

    f32x4 acc[4][NF];
#pragma unroll
    for (int m = 0; m < 4; ++m)
#pragma unroll
        for (int n = 0; n < NF; ++n)
            acc[m][n] = (f32x4){0.f, 0.f, 0.f, 0.f};

    uint2  yreg[2][RPT];
    float4 wv[2][8];
    bf16x8 wh[4], wl[4];
    u32 yhw[2][RPT / 2], ylw[2][RPT / 2];

    auto loadY = [&](int ybuf, int k0) {
#pragma unroll
        for (int r = 0; r < RPT; ++r)
            yreg[ybuf][r] = *(const uint2*)(Yblk + (size_t)(k0 + trow + r) * 64 + col0);
    };
    auto loadWf32 = [&](int wbuf, int k0) {
#pragma unroll
        for (int m = 0; m < 4; ++m) {
            const float* wr = Wf + wbase + (size_t)(wave * 64 + m * 16 + l16) * 256 + k0 + lk * 8;
            wv[wbuf][2 * m]     = *(const float4*)wr;
            wv[wbuf][2 * m + 1] = *(const float4*)(wr + 4);
        }
    };
    auto convW = [&](int wbuf) {
#pragma unroll
        for (int m = 0; m < 4; ++m) {
            const float f[8] = { wv[wbuf][2 * m].x,     wv[wbuf][2 * m].y,
                                 wv[wbuf][2 * m].z,     wv[wbuf][2 * m].w,
                                 wv[wbuf][2 * m + 1].x, wv[wbuf][2 * m + 1].y,
                                 wv[wbuf][2 * m + 1].z, wv[wbuf][2 * m + 1].w };
            union { bf16x8 v; u16 u[8]; } H, L;
#pragma unroll
            for (int e = 0; e < 8; ++e) {
                const u16 hh = bf16_rn(f[e]);
                H.u[e] = hh;
                L.u[e] = bf16_rn(f[e] - bf16_to_f(hh));
            }
            wh[m] = H.v;
            wl[m] = L.v;
        }
    };

    loadWf32(0, 0); loadY(0, 0); loadWf32(1, 32); loadY(1, 32);

#pragma unroll
    for (int it = 0; it < 8; ++it) {
        const int k0 = it * 32;
        const int cur = it & 1;
        convW(cur);
#pragma unroll
        for (int c = 0; c < 2; ++c)
#pragma unroll
            for (int j2 = 0; j2 < RPT / 2; ++j2) {
                const u32 a = c ? yreg[cur][2 * j2].y     : yreg[cur][2 * j2].x;
                const u32 b = c ? yreg[cur][2 * j2 + 1].y : yreg[cur][2 * j2 + 1].x;
                yhw[c][j2] = (a & 0xFFFFu) | (b << 16);
                ylw[c][j2] = (a >> 16)     | (b & 0xFFFF0000u);
            }
        bar_lds();
#pragma unroll
        for (int c = 0; c < 2; ++c) {
            *(uint2*)&Yhi_s[(col0 + c) * LD + trow] = make_uint2(yhw[c][0], yhw[c][1]);
            *(uint2*)&Ylo_s[(col0 + c) * LD + trow] = make_uint2(ylw[c][0], ylw[c][1]);
        }
        bar_lds();
        if (it + 2 < 8) { loadWf32(cur, k0 + 64); loadY(cur, k0 + 64); }
        __builtin_amdgcn_s_setprio(1);
#pragma unroll
        for (int n = 0; n < NF; ++n) {
            const int ccol = n * 16 + l16;
            const bf16x8 bhi = *(const bf16x8*)&Yhi_s[ccol * LD + 8 * lk];
            const bf16x8 blo = *(const bf16x8*)&Ylo_s[ccol * LD + 8 * lk];
#pragma unroll
            for (int m = 0; m < 4; ++m)
                acc[m][n] = __builtin_amdgcn_mfma_f32_16x16x32_bf16(wh[m], bhi, acc[m][n], 0, 0, 0);
#pragma unroll
            for (int m = 0; m < 4; ++m)
                acc[m][n] = __builtin_amdgcn_mfma_f32_16x16x32_bf16(wh[m], blo, acc[m][n], 0, 0, 0);
#pragma unroll
            for (int m = 0; m < 4; ++m)
                acc[m][n] = __builtin_amdgcn_mfma_f32_16x16x32_bf16(wl[m], bhi, acc[m][n], 0, 0, 0);
        }
        __builtin_amdgcn_s_setprio(0);
    }

    // ---- fused final: per-wave child block, within-wave reduce over channels ----
    const int gy = bid >> 5, gx = bid & 31;
    const int cy = 2 * gy + (wave >> 1), cx = 2 * gx + (wave & 1);
    const int blk = cy * 64 + cx;
    float wf0v[4][4], wf2v[4][4], biv[4][4];
#pragma unroll
    for (int m = 0; m < 4; ++m)
#pragma unroll
        for (int r = 0; r < 4; ++r) {
            const int cch = m * 16 + lk * 4 + r;
            wf0v[m][r] = wf[(size_t)blk * 256 + cch];
            wf2v[m][r] = wf[(size_t)blk * 256 + 128 + cch];
            biv[m][r]  = bias[(size_t)bid * 256 + wave * 64 + cch];
        }
    const float bf0 = bff[blk * 4 + 0], bf2 = bff[blk * 4 + 2];
#pragma unroll
    for (int n = 0; n < 4; ++n) {
        float a0 = 0.f, a2 = 0.f;
#pragma unroll
        for (int m = 0; m < 4; ++m)
#pragma unroll
            for (int r = 0; r < 4; ++r) {
                const float y = fmaxf(acc[m][n][r] + biv[m][r], 0.f);
                a0 = fmaf(y, wf0v[m][r], a0);
                a2 = fmaf(y, wf2v[m][r], a2);
            }
        a0 += __shfl_xor(a0, 16); a0 += __shfl_xor(a0, 32);
        a2 += __shfl_xor(a2, 16); a2 += __shfl_xor(a2, 32);
        if (lk == n) {
            const float o0 = fmaxf(a0 + bf0, 0.f);
            const float o2 = fmaxf(a2 + bf2, 0.f);
            out[(size_t)(n * 16 + l16) * 4096 + blk] = (o0 - o2) * (1.0f / 4096.0f);
        }
    }
}

extern "C" void kernel_launch(void* const* d_in, const int* in_sizes, int n_in,
                              void* d_out, int out_size, void* d_ws, size_t ws_size,
                              hipStream_t stream) {
    (void)in_sizes; (void)n_in; (void)out_size; (void)ws_size;

    const float* xr = (const float*)d_in[0];
    const float* xi = (const float*)d_in[1];
    const float* w0 = (const float*)d_in[2];
    const float* b0 = (const float*)d_in[3];
    const float* wrec[5] = { (const float*)d_in[4],  (const float*)d_in[6],
                             (const float*)d_in[8],  (const float*)d_in[10],
                             (const float*)d_in[12] };
    const float* brec[5] = { (const float*)d_in[5],  (const float*)d_in[7],
                             (const float*)d_in[9],  (const float*)d_in[11],
                             (const float*)d_in[13] };
    const float* wf = (const float*)d_in[14];
    const float* bf = (const float*)d_in[15];
    float* out = (float*)d_out;

    u32* bufA = (u32*)d_ws;
    u32* bufB = bufA + (size_t)PLANE;
    u16* wc1  = (u16*)(bufB + (size_t)PLANE);
    u16* wc2  = wc1 + (size_t)2 * 262144;
    u16* wc3  = wc2 + (size_t)2 * 1048576;

    wconv_kernel<<<(262144 / 8 + 255) / 256, 256, 0, stream>>>(wrec[0], wc1, wc1 + 262144, 262144 / 8);
    wconv_kernel<<<(1048576 / 8 + 255) / 256, 256, 0, stream>>>(wrec[1], wc2, wc2 + 1048576, 1048576 / 8);
    wconv_kernel<<<(4194304 / 8 + 255) / 256, 256, 0, stream>>>(wrec[2], wc3, wc3 + 4194304, 4194304 / 8);

    layer0_kernel<<<dim3(256, 2), 256, 0, stream>>>(xr, xi, w0, b0, bufA);

    // layer 1: G=2,  S2=16, Nb=16384
    rec_mfma_kernel<128, true><<<dim3(128, 1, 4), 256, 0, stream>>>(
        bufA, nullptr, wc1, wc1 + 262144, brec[0], bufB, 1, 4);
    // layer 2: G=4,  S2=8,  Nb=4096
    rec_mfma_kernel<128, true><<<dim3(32, 1, 16), 256, 0, stream>>>(
        bufB, nullptr, wc2, wc2 + 1048576, brec[1], bufA, 2, 3);
    // layer 3: G=8,  S2=4,  Nb=1024
    rec_mfma_kernel<128, true><<<dim3(8, 1, 64), 256, 0, stream>>>(
        bufA, nullptr, wc3, wc3 + 4194304, brec[2], bufB, 3, 2);
    // layer 4: G=16, S2=2,  Nb=256 (NT=64 -> 4 n-tiles, acc pressure halved)
    rec_mfma_kernel<64, false><<<dim3(4, 1, 256), 256, 0, stream>>>(
        bufB, wrec[3], nullptr, nullptr, brec[3], bufA, 4, 1);
    // layer 5 + final fused: G=32, Nb=64
    rec5_final_kernel<<<1024, 256, 0, stream>>>(bufA, wrec[4], brec[4], wf, bf, out);
}

// Round 7
// 270.570 us; speedup vs baseline: 1.7765x; 1.1832x over previous
//
#include <hip/hip_runtime.h>
#include <cstddef>

// ButterFlyNet2D IDFT forward. Split-bf16 MFMA (3-pass: Whi*Yhi + Whi*Ylo + Wlo*Yhi).
// Activations: ONE u32 per element = packed (hi bf16 | lo bf16<<16).
//   Plane layout A[gy][gx][i][k][l][b][p][q] -> per block contiguous Y[256][Nb].
// R7: L4+L5+final fused into one kernel (1024 wg, one per L5 block):
//   stage-1: T[64][256] = relu(W4slice . Y4) -- no LDS, no barriers, all operands
//            direct global->register with depth-2 prefetch.
//   stage-2: L5 GEMM via small LDS K-windows (acc1[kw] -> window kw), W5 direct,
//            bar_lds barriers never drain vmcnt. Final 1x1 fused epilogue.
// Sibling wgs (same parent) mapped to the same XCD so Y4's 4x re-read is L2-hot.

typedef unsigned int  u32;
typedef unsigned short u16;
typedef __attribute__((ext_vector_type(8))) short bf16x8;
typedef __attribute__((ext_vector_type(4))) float f32x4;

#define PLANE 16777216   // elements per activation buffer

__device__ inline u16 bf16_rn(float x) {
    u32 u = __builtin_bit_cast(u32, x);
    u32 r = (u + 0x7FFFu + ((u >> 16) & 1u)) >> 16;
    return (u16)r;
}
__device__ inline float bf16_to_f(u16 h) {
    u32 u = ((u32)h) << 16;
    return __builtin_bit_cast(float, u);
}
__device__ inline u32 pack_split(float v) {
    const u16 h = bf16_rn(v);
    const u16 l = bf16_rn(v - bf16_to_f(h));
    return (u32)h | ((u32)l << 16);
}
// LDS-only barrier: drains ds ops, leaves global loads (vmcnt) in flight.
__device__ inline void bar_lds() {
    asm volatile("s_waitcnt lgkmcnt(0)\n\ts_barrier" ::: "memory");
}

// ---------------- weight pre-convert (layers 1-3, one launch) ----------------
__global__ __launch_bounds__(256)
void wconv_all_kernel(const float* __restrict__ s1, const float* __restrict__ s2,
                      const float* __restrict__ s3,
                      u16* __restrict__ d1, u16* __restrict__ d2, u16* __restrict__ d3) {
    const int i = blockIdx.x * 256 + threadIdx.x;   // 8-elem group, 688128 total
    const float* s; u16 *dh, *dl; int off;
    if (i < 32768)        { s = s1; dh = d1; dl = d1 + 262144;  off = i; }
    else if (i < 163840)  { s = s2; dh = d2; dl = d2 + 1048576; off = i - 32768; }
    else                  { s = s3; dh = d3; dl = d3 + 4194304; off = i - 163840; }
    const float4 a = *(const float4*)(s + 8 * off);
    const float4 b = *(const float4*)(s + 8 * off + 4);
    union { bf16x8 v; u16 u[8]; } H, L;
    const float f[8] = {a.x, a.y, a.z, a.w, b.x, b.y, b.z, b.w};
#pragma unroll
    for (int e = 0; e < 8; ++e) {
        const u16 h = bf16_rn(f[e]);
        H.u[e] = h;
        L.u[e] = bf16_rn(f[e] - bf16_to_f(h));
    }
    *(bf16x8*)(dh + 8 * off) = H.v;
    *(bf16x8*)(dl + 8 * off) = L.v;
}

// ---------------- Layer 0: x read once, 128 outputs per thread ----------------
__global__ __launch_bounds__(256)
void layer0_kernel(const float* __restrict__ xr, const float* __restrict__ xi,
                   const float* __restrict__ w0, const float* __restrict__ b0,
                   u32* __restrict__ A1) {
    __shared__ float w0s[128][16];
    __shared__ float b0s[128];
    const int og  = blockIdx.y;             // 0/1: o = og*128 + j
    const int tid = threadIdx.x;
    {
        const int row = tid >> 1, half = tid & 1;
        const float4 wa = *(const float4*)(w0 + (og * 128 + row) * 16 + half * 8);
        const float4 wb = *(const float4*)(w0 + (og * 128 + row) * 16 + half * 8 + 4);
        *(float4*)&w0s[row][half * 8]     = wa;
        *(float4*)&w0s[row][half * 8 + 4] = wb;
        if (tid < 128) b0s[tid] = b0[og * 128 + tid];
    }
    __syncthreads();

    const int n = blockIdx.x * 256 + tid;   // output pixel: b*1024 + p*32 + q
    const int b = n >> 10, p = (n >> 5) & 31, q = n & 31;
    float xs[16];
#pragma unroll
    for (int k = 0; k < 2; ++k) {
        const float2 vr = *(const float2*)(xr + b * 4096 + (2 * p + k) * 64 + 2 * q);
        const float2 vi = *(const float2*)(xi + b * 4096 + (2 * p + k) * 64 + 2 * q);
        xs[0  + k * 2 + 0] = fmaxf(vr.x, 0.f);  xs[0  + k * 2 + 1] = fmaxf(vr.y, 0.f);
        xs[4  + k * 2 + 0] = fmaxf(vi.x, 0.f);  xs[4  + k * 2 + 1] = fmaxf(vi.y, 0.f);
        xs[8  + k * 2 + 0] = fmaxf(-vr.x, 0.f); xs[8  + k * 2 + 1] = fmaxf(-vr.y, 0.f);
        xs[12 + k * 2 + 0] = fmaxf(-vi.x, 0.f); xs[12 + k * 2 + 1] = fmaxf(-vi.y, 0.f);
    }
    const int kp = p & 1, lp = q & 1, pp = p >> 1, qp = q >> 1;
    const size_t pixoff = (size_t)(b * 256 + pp * 16 + qp);
#pragma unroll
    for (int j = 0; j < 128; ++j) {
        float acc = b0s[j];
#pragma unroll
        for (int e = 0; e < 16; ++e) acc = fmaf(xs[e], w0s[j][e], acc);
        acc = fmaxf(acc, 0.f);
        const int o = og * 128 + j;
        const int gy = o >> 7, gx = (o >> 6) & 1, c = o & 63;
        const size_t flat = (size_t)((((gy * 2 + gx) * 64 + c) * 2 + kp) * 2 + lp) * (64 * 256)
                          + pixoff;
        A1[flat] = pack_split(acc);
    }
}

// ---------------- Recursion layers 1..3 : split-bf16 MFMA, W direct ----------------
template<int NT>
__global__ __launch_bounds__(256, 2)
void rec_mfma_kernel(const u32* __restrict__ Yg,
                     const u16* __restrict__ Whi_g, const u16* __restrict__ Wlo_g,
                     const float* __restrict__ bias, u32* __restrict__ Aout,
                     const int lgG, const int lgS2) {
    constexpr int NF  = NT / 16;
    constexpr int LD  = 40;
    constexpr int NCP = NT / 2;
    constexpr int RPT = 32 / (256 / NCP);

    __shared__ u16 Yhi_s[NT * LD];
    __shared__ u16 Ylo_s[NT * LD];

    const int G  = 1 << lgG;
    const int S2 = 1 << lgS2;
    const int Nb = 64 << (2 * lgS2);

    // XCD-chunked swizzle: keep all n-tiles of a block on one XCD (W L2 reuse)
    int bid, nt;
    const int nBid = G * G, NTILES = gridDim.x;
    if (nBid >= 8) {
        const int h = blockIdx.z * NTILES + blockIdx.x;
        const int xcd = h & 7, j = h >> 3, per = nBid >> 3;
        bid = xcd * per + j / NTILES;
        nt  = j % NTILES;
    } else { bid = blockIdx.z; nt = blockIdx.x; }

    const size_t wbase = (size_t)bid * 65536;
    const u32* Yblk = Yg + (size_t)bid * 256 * (size_t)Nb + (size_t)nt * NT;

    const int tid = threadIdx.x, wave = tid >> 6, lane = tid & 63;
    const int l16 = lane & 15, lk = lane >> 4;
    const int cp = tid % NCP, rg = tid / NCP;
    const int col0 = cp * 2, trow = rg * RPT;

    f32x4 acc[4][NF];
#pragma unroll
    for (int m = 0; m < 4; ++m)
#pragma unroll
        for (int n = 0; n < NF; ++n)
            acc[m][n] = (f32x4){0.f, 0.f, 0.f, 0.f};

    uint2  yreg[2][RPT];
    bf16x8 wh[4], wl[4];
    u32 yhw[2][RPT / 2], ylw[2][RPT / 2];

    auto loadY = [&](int ybuf, int k0) {
#pragma unroll
        for (int r = 0; r < RPT; ++r)
            yreg[ybuf][r] = *(const uint2*)(Yblk + (size_t)(k0 + trow + r) * Nb + col0);
    };
    auto loadWpre = [&](int k0) {
#pragma unroll
        for (int m = 0; m < 4; ++m) {
            const size_t off = wbase + (size_t)(wave * 64 + m * 16 + l16) * 256 + k0 + lk * 8;
            wh[m] = *(const bf16x8*)(Whi_g + off);
            wl[m] = *(const bf16x8*)(Wlo_g + off);
        }
    };
    auto prepY = [&](int ybuf) {
#pragma unroll
        for (int c = 0; c < 2; ++c)
#pragma unroll
            for (int j2 = 0; j2 < RPT / 2; ++j2) {
                const u32 a = c ? yreg[ybuf][2 * j2].y     : yreg[ybuf][2 * j2].x;
                const u32 b = c ? yreg[ybuf][2 * j2 + 1].y : yreg[ybuf][2 * j2 + 1].x;
                yhw[c][j2] = (a & 0xFFFFu) | (b << 16);
                ylw[c][j2] = (a >> 16)     | (b & 0xFFFF0000u);
            }
    };
    auto stageY = [&]() {
#pragma unroll
        for (int c = 0; c < 2; ++c) {
            if constexpr (RPT == 8) {
                *(uint4*)&Yhi_s[(col0 + c) * LD + trow] = make_uint4(yhw[c][0], yhw[c][1], yhw[c][2], yhw[c][3]);
                *(uint4*)&Ylo_s[(col0 + c) * LD + trow] = make_uint4(ylw[c][0], ylw[c][1], ylw[c][2], ylw[c][3]);
            } else {
                *(uint2*)&Yhi_s[(col0 + c) * LD + trow] = make_uint2(yhw[c][0], yhw[c][1]);
                *(uint2*)&Ylo_s[(col0 + c) * LD + trow] = make_uint2(ylw[c][0], ylw[c][1]);
            }
        }
    };

    loadY(0, 0); loadY(1, 32);

#pragma unroll
    for (int it = 0; it < 8; ++it) {
        const int k0 = it * 32;
        const int cur = it & 1;
        loadWpre(k0);            // in flight across barriers (no vmcnt drain)
        prepY(cur);              // waits on yreg[cur] (issued 2 iters ago)
        bar_lds();               // prev MFMA ds_reads done; LDS reusable
        stageY();
        bar_lds();               // Y tile visible
        if (it + 2 < 8) loadY(cur, k0 + 64);
        __builtin_amdgcn_s_setprio(1);
#pragma unroll
        for (int n = 0; n < NF; ++n) {
            const int ccol = n * 16 + l16;
            const bf16x8 bhi = *(const bf16x8*)&Yhi_s[ccol * LD + 8 * lk];
            const bf16x8 blo = *(const bf16x8*)&Ylo_s[ccol * LD + 8 * lk];
#pragma unroll
            for (int m = 0; m < 4; ++m)
                acc[m][n] = __builtin_amdgcn_mfma_f32_16x16x32_bf16(wh[m], bhi, acc[m][n], 0, 0, 0);
#pragma unroll
            for (int m = 0; m < 4; ++m)
                acc[m][n] = __builtin_amdgcn_mfma_f32_16x16x32_bf16(wh[m], blo, acc[m][n], 0, 0, 0);
#pragma unroll
            for (int m = 0; m < 4; ++m)
                acc[m][n] = __builtin_amdgcn_mfma_f32_16x16x32_bf16(wl[m], bhi, acc[m][n], 0, 0, 0);
        }
        __builtin_amdgcn_s_setprio(0);
    }

    // ---- epilogue: bias + relu + packed scatter to child blocks ----
    const int gy = bid >> lgG, gx = bid & (G - 1);
    const int NS2 = S2 >> 1;
#pragma unroll
    for (int m = 0; m < 4; ++m) {
#pragma unroll
        for (int r = 0; r < 4; ++r) {
            const int oc = wave * 64 + m * 16 + lk * 4 + r;   // C/D: row=(lane>>4)*4+reg
            const float bi = bias[(size_t)bid * 256 + oc];
            const int yl = oc >> 7, xl = (oc >> 6) & 1, cch = oc & 63;
            const int cy = 2 * gy + yl, cx = 2 * gx + xl;
            const size_t base = (size_t)((cy * (2 * G) + cx) * 64 + cch);
#pragma unroll
            for (int n = 0; n < NF; ++n) {
                const float v = fmaxf(acc[m][n][r] + bi, 0.f);
                const int ng = nt * NT + n * 16 + l16;        // C/D: col=lane&15
                const int b   = ng >> (2 * lgS2);
                const int rem = ng & ((1 << (2 * lgS2)) - 1);
                const int p = rem >> lgS2, q = rem & (S2 - 1);
                const size_t flat = ((base * 2 + (p & 1)) * 2 + (q & 1)) * (size_t)(64 * NS2 * NS2)
                                  + (size_t)(b * NS2 * NS2 + (p >> 1) * NS2 + (q >> 1));
                Aout[flat] = pack_split(v);
            }
        }
    }
}

// ---------------- Fused L4 + L5 + final ----------------
// One wg per L5 block (cy,cx). Stage-1: T[64][256] = relu(b4 + W4slice . Y4)
// (Y4 = parent L4 input block; W4slice = the child's 64 oc rows). Stage-2:
// O[256][64] = L5 GEMM with B = T (via LDS K-windows). Final 1x1 in epilogue.
__global__ __launch_bounds__(256, 2)
void rec45_final_kernel(const u32* __restrict__ Yg, const float* __restrict__ W4,
                        const float* __restrict__ b4, const float* __restrict__ W5,
                        const float* __restrict__ b5, const float* __restrict__ wf,
                        const float* __restrict__ bff, float* __restrict__ out) {
    constexpr int LDW = 72;                 // window row stride (u16); 144 B, 16-mult
    __shared__ u16 Whi_w[64 * LDW];
    __shared__ u16 Wlo_w[64 * LDW];

    // sibling wgs (same parent) => same id mod 8 => same XCD (Y4 L2 reuse);
    // resident 512 wgs = 128 parents x 4 children => 16 parents/XCD = 4 MB L2.
    const int h = blockIdx.x;
    const int parent = ((h >> 5) << 3) | (h & 7);   // 0..255 = pgy*16+pgx
    const int child  = (h >> 3) & 3;                // = ylc*2+xlc
    const int pgy = parent >> 4, pgx = parent & 15;
    const int cy = 2 * pgy + (child >> 1), cx = 2 * pgx + (child & 1);
    const int bid5 = cy * 32 + cx;
    const int ocbase = child * 64;                  // ylc*128 + xlc*64

    const u32* Yblk  = Yg + (size_t)parent * 65536;                      // [256][256]
    const float* W4s = W4 + (size_t)parent * 65536 + (size_t)ocbase * 256; // [64][256]
    const float* W5b = W5 + (size_t)bid5 * 65536;

    const int tid = threadIdx.x, wave = tid >> 6, lane = tid & 63;
    const int l16 = lane & 15, lk = lane >> 4;

    f32x4 acc1[4][4];
#pragma unroll
    for (int m = 0; m < 4; ++m)
#pragma unroll
        for (int n = 0; n < 4; ++n)
            acc1[m][n] = (f32x4){0.f, 0.f, 0.f, 0.f};

    u32    yf[2][4][8];    // direct-global Y B-frags (depth-2)
    float4 wv[2][8];       // f32 W staging (depth-2) -- stage-1: W4, stage-2: W5
    bf16x8 wh[4], wl[4];

    auto loadY = [&](int buf, int k0) {
#pragma unroll
        for (int n = 0; n < 4; ++n)
#pragma unroll
            for (int j = 0; j < 8; ++j)
                yf[buf][n][j] = Yblk[(size_t)(k0 + 8 * lk + j) * 256 + wave * 64 + n * 16 + l16];
    };
    auto loadW4 = [&](int buf, int k0) {
#pragma unroll
        for (int m = 0; m < 4; ++m) {
            const float* p = W4s + (size_t)(m * 16 + l16) * 256 + k0 + lk * 8;
            wv[buf][2 * m]     = *(const float4*)p;
            wv[buf][2 * m + 1] = *(const float4*)(p + 4);
        }
    };
    auto loadW5 = [&](int buf, int t) {
#pragma unroll
        for (int m = 0; m < 4; ++m) {
            const float* p = W5b + (size_t)(wave * 64 + m * 16 + l16) * 256 + t * 32 + lk * 8;
            wv[buf][2 * m]     = *(const float4*)p;
            wv[buf][2 * m + 1] = *(const float4*)(p + 4);
        }
    };
    auto convW = [&](int buf) {
#pragma unroll
        for (int m = 0; m < 4; ++m) {
            const float f[8] = { wv[buf][2 * m].x,     wv[buf][2 * m].y,
                                 wv[buf][2 * m].z,     wv[buf][2 * m].w,
                                 wv[buf][2 * m + 1].x, wv[buf][2 * m + 1].y,
                                 wv[buf][2 * m + 1].z, wv[buf][2 * m + 1].w };
            union { bf16x8 v; u16 u[8]; } H, L;
#pragma unroll
            for (int e = 0; e < 8; ++e) {
                const u16 hh = bf16_rn(f[e]);
                H.u[e] = hh;
                L.u[e] = bf16_rn(f[e] - bf16_to_f(hh));
            }
            wh[m] = H.v;
            wl[m] = L.v;
        }
    };

    // ---- stage 1: no LDS, no barriers ----
    loadY(0, 0); loadW4(0, 0); loadY(1, 32); loadW4(1, 32);
#pragma unroll
    for (int it = 0; it < 8; ++it) {
        const int cur = it & 1;
        convW(cur);
        __builtin_amdgcn_s_setprio(1);
#pragma unroll
        for (int n = 0; n < 4; ++n) {
            union { bf16x8 v; u16 u[8]; } BH, BL;
#pragma unroll
            for (int j = 0; j < 8; ++j) {
                const u32 y = yf[cur][n][j];
                BH.u[j] = (u16)y;
                BL.u[j] = (u16)(y >> 16);
            }
#pragma unroll
            for (int m = 0; m < 4; ++m)
                acc1[m][n] = __builtin_amdgcn_mfma_f32_16x16x32_bf16(wh[m], BH.v, acc1[m][n], 0, 0, 0);
#pragma unroll
            for (int m = 0; m < 4; ++m)
                acc1[m][n] = __builtin_amdgcn_mfma_f32_16x16x32_bf16(wh[m], BL.v, acc1[m][n], 0, 0, 0);
#pragma unroll
            for (int m = 0; m < 4; ++m)
                acc1[m][n] = __builtin_amdgcn_mfma_f32_16x16x32_bf16(wl[m], BH.v, acc1[m][n], 0, 0, 0);
        }
        __builtin_amdgcn_s_setprio(0);
        if (it + 2 < 8) { loadY(cur, 32 * it + 64); loadW4(cur, 32 * it + 64); }
    }

    // ---- stage 2: K-windows of 64 (window kw = acc1[kw]), W5 depth-2 ----
    f32x4 acc2[4][4];
#pragma unroll
    for (int m = 0; m < 4; ++m)
#pragma unroll
        for (int n = 0; n < 4; ++n)
            acc2[m][n] = (f32x4){0.f, 0.f, 0.f, 0.f};

    float b4v[4][4];
#pragma unroll
    for (int kw = 0; kw < 4; ++kw)
#pragma unroll
        for (int r = 0; r < 4; ++r)
            b4v[kw][r] = b4[(size_t)parent * 256 + ocbase + kw * 16 + lk * 4 + r];

    loadW5(0, 0); loadW5(1, 1);

#pragma unroll
    for (int kw = 0; kw < 4; ++kw) {
        // write window kw: k_global = i*4 + par, i = kw*16 + lk*4 + r (stage-1 row)
#pragma unroll
        for (int n = 0; n < 4; ++n) {
            const int colg = wave * 64 + n * 16 + l16;
            const int b_ = colg >> 2, par = colg & 3;
#pragma unroll
            for (int r = 0; r < 4; ++r) {
                const float v = fmaxf(acc1[kw][n][r] + b4v[kw][r], 0.f);
                const int k_ = lk * 16 + r * 4 + par;   // window-relative
                const u16 hh = bf16_rn(v);
                Whi_w[b_ * LDW + k_] = hh;
                Wlo_w[b_ * LDW + k_] = bf16_rn(v - bf16_to_f(hh));
            }
        }
        bar_lds();                       // window visible (global loads stay in flight)
#pragma unroll
        for (int kc = 0; kc < 2; ++kc) {
            const int t = kw * 2 + kc;
            const int cur = t & 1;
            convW(cur);                  // waits on W5 chunk t (issued 2 chunks ago)
            __builtin_amdgcn_s_setprio(1);
#pragma unroll
            for (int n = 0; n < 4; ++n) {
                const int b_ = n * 16 + l16;
                const bf16x8 bhi = *(const bf16x8*)&Whi_w[b_ * LDW + kc * 32 + 8 * lk];
                const bf16x8 blo = *(const bf16x8*)&Wlo_w[b_ * LDW + kc * 32 + 8 * lk];
#pragma unroll
                for (int m = 0; m < 4; ++m)
                    acc2[m][n] = __builtin_amdgcn_mfma_f32_16x16x32_bf16(wh[m], bhi, acc2[m][n], 0, 0, 0);
#pragma unroll
                for (int m = 0; m < 4; ++m)
                    acc2[m][n] = __builtin_amdgcn_mfma_f32_16x16x32_bf16(wh[m], blo, acc2[m][n], 0, 0, 0);
#pragma unroll
                for (int m = 0; m < 4; ++m)
                    acc2[m][n] = __builtin_amdgcn_mfma_f32_16x16x32_bf16(wl[m], bhi, acc2[m][n], 0, 0, 0);
            }
            __builtin_amdgcn_s_setprio(0);
            if (t + 2 < 8) loadW5(cur, t + 2);
        }
        bar_lds();                       // reads of window kw done before next write
    }

    // ---- fused final: per-wave child block, within-wave reduce over channels ----
    const int fy = 2 * cy + (wave >> 1), fx = 2 * cx + (wave & 1);
    const int blk = fy * 64 + fx;
    float wf0v[4][4], wf2v[4][4], biv[4][4];
#pragma unroll
    for (int m = 0; m < 4; ++m)
#pragma unroll
        for (int r = 0; r < 4; ++r) {
            const int cch = m * 16 + lk * 4 + r;
            wf0v[m][r] = wf[(size_t)blk * 256 + cch];
            wf2v[m][r] = wf[(size_t)blk * 256 + 128 + cch];
            biv[m][r]  = b5[(size_t)bid5 * 256 + wave * 64 + cch];
        }
    const float bf0 = bff[blk * 4 + 0], bf2 = bff[blk * 4 + 2];
#pragma unroll
    for (int n = 0; n < 4; ++n) {
        float a0 = 0.f, a2 = 0.f;
#pragma unroll
        for (int m = 0; m < 4; ++m)
#pragma unroll
            for (int r = 0; r < 4; ++r) {
                const float y = fmaxf(acc2[m][n][r] + biv[m][r], 0.f);
                a0 = fmaf(y, wf0v[m][r], a0);
                a2 = fmaf(y, wf2v[m][r], a2);
            }
        a0 += __shfl_xor(a0, 16); a0 += __shfl_xor(a0, 32);
        a2 += __shfl_xor(a2, 16); a2 += __shfl_xor(a2, 32);
        if (lk == n) {
            const float o0 = fmaxf(a0 + bf0, 0.f);
            const float o2 = fmaxf(a2 + bf2, 0.f);
            out[(size_t)(n * 16 + l16) * 4096 + blk] = (o0 - o2) * (1.0f / 4096.0f);
        }
    }
}

extern "C" void kernel_launch(void* const* d_in, const int* in_sizes, int n_in,
                              void* d_out, int out_size, void* d_ws, size_t ws_size,
                              hipStream_t stream) {
    (void)in_sizes; (void)n_in; (void)out_size; (void)ws_size;

    const float* xr = (const float*)d_in[0];
    const float* xi = (const float*)d_in[1];
    const float* w0 = (const float*)d_in[2];
    const float* b0 = (const float*)d_in[3];
    const float* wrec[5] = { (const float*)d_in[4],  (const float*)d_in[6],
                             (const float*)d_in[8],  (const float*)d_in[10],
                             (const float*)d_in[12] };
    const float* brec[5] = { (const float*)d_in[5],  (const float*)d_in[7],
                             (const float*)d_in[9],  (const float*)d_in[11],
                             (const float*)d_in[13] };
    const float* wf = (const float*)d_in[14];
    const float* bf = (const float*)d_in[15];
    float* out = (float*)d_out;

    u32* bufA = (u32*)d_ws;
    u32* bufB = bufA + (size_t)PLANE;
    u16* wc1  = (u16*)(bufB + (size_t)PLANE);
    u16* wc2  = wc1 + (size_t)2 * 262144;
    u16* wc3  = wc2 + (size_t)2 * 1048576;

    wconv_all_kernel<<<2688, 256, 0, stream>>>(wrec[0], wrec[1], wrec[2], wc1, wc2, wc3);

    layer0_kernel<<<dim3(256, 2), 256, 0, stream>>>(xr, xi, w0, b0, bufA);

    // layer 1: G=2,  S2=16, Nb=16384
    rec_mfma_kernel<128><<<dim3(128, 1, 4), 256, 0, stream>>>(
        bufA, wc1, wc1 + 262144, brec[0], bufB, 1, 4);
    // layer 2: G=4,  S2=8,  Nb=4096
    rec_mfma_kernel<128><<<dim3(32, 1, 16), 256, 0, stream>>>(
        bufB, wc2, wc2 + 1048576, brec[1], bufA, 2, 3);
    // layer 3: G=8,  S2=4,  Nb=1024
    rec_mfma_kernel<128><<<dim3(8, 1, 64), 256, 0, stream>>>(
        bufA, wc3, wc3 + 4194304, brec[2], bufB, 3, 2);
    // layers 4+5+final fused: one wg per L5 block
    rec45_final_kernel<<<1024, 256, 0, stream>>>(
        bufB, wrec[3], brec[3], wrec[4], brec[4], wf, bf, out);
}